// Round 6
// baseline (607.571 us; speedup 1.0000x reference)
//
#include <hip/hip_runtime.h>
#include <hip/hip_bf16.h>
#include <math.h>

// ---------------- graph structure ----------------

__global__ void count_indeg(const int* __restrict__ dst, int e, int* __restrict__ indeg) {
    int i = blockIdx.x * blockDim.x + threadIdx.x;
    if (i < e) atomicAdd(&indeg[dst[i]], 1);
}

__global__ void compute_dinv(const int* __restrict__ indeg, float* __restrict__ dinv, int n) {
    int i = blockIdx.x * blockDim.x + threadIdx.x;
    if (i < n) {
        float deg = (float)(indeg[i] + 1);   // + self loop, always >= 1
        dinv[i] = 1.0f / sqrtf(deg);
    }
}

__global__ void make_ranges(const int* __restrict__ indeg, int* __restrict__ start,
                            int* __restrict__ cursor, int* __restrict__ counter, int n) {
    int i = blockIdx.x * blockDim.x + threadIdx.x;
    if (i < n) {
        int s = atomicAdd(counter, indeg[i]);
        start[i] = s;
        cursor[i] = s;
    }
}

__global__ void fill_csr(const int* __restrict__ src, const int* __restrict__ dst, int e,
                         int* __restrict__ cursor, int* __restrict__ ssrc) {
    int i = blockIdx.x * blockDim.x + threadIdx.x;
    if (i < e) {
        int p = atomicAdd(&cursor[dst[i]], 1);
        if (p >= 0 && p < e) ssrc[p] = src[i];
    }
}

// ---------------- weight fake-quant (symmetric 4-bit) ----------------

__global__ void quant_w(const float* __restrict__ w, const float* __restrict__ a,
                        float* __restrict__ wq, int n) {
    int i = blockIdx.x * blockDim.x + threadIdx.x;
    if (i < n) {
        float s = a[0];
        float v = w[i] / s;
        v = fminf(fmaxf(v, -8.0f), 7.0f);
        wq[i] = rintf(v) * s;   // round-half-even, matches jnp.round
    }
}

// ---------------- tiled GEMM: C[M,N] = A[M,K] @ B[K,N] + rs[row]*bias[N] ----------------

#define TM 128
#define TN 64
#define TK 16

__global__ __launch_bounds__(256) void gemm_bias_tiled(
        const float* __restrict__ A, const float* __restrict__ B,
        const float* __restrict__ bias, const float* __restrict__ rowsum,
        float* __restrict__ C, int M, int N, int K) {
    __shared__ float sA[TK][TM + 4];
    __shared__ float sB[TK][TN + 4];
    int tid = threadIdx.x;
    int rowBase = blockIdx.x * TM;
    int colBase = blockIdx.y * TN;
    int tx = tid & 15;
    int ty = tid >> 4;
    float acc[8][4] = {};

    int aRow = tid >> 1;
    int aK   = (tid & 1) * 8;
    int bK   = tid >> 4;
    int bCol = (tid & 15) * 4;

    for (int k0 = 0; k0 < K; k0 += TK) {
        int gRow = rowBase + aRow;
        if (gRow >= M) gRow = M - 1;            // clamp; discarded at store
        const float* ap = A + (size_t)gRow * K + k0 + aK;
        float4 a0 = *(const float4*)ap;
        float4 a1 = *(const float4*)(ap + 4);
        sA[aK + 0][aRow] = a0.x;
        sA[aK + 1][aRow] = a0.y;
        sA[aK + 2][aRow] = a0.z;
        sA[aK + 3][aRow] = a0.w;
        sA[aK + 4][aRow] = a1.x;
        sA[aK + 5][aRow] = a1.y;
        sA[aK + 6][aRow] = a1.z;
        sA[aK + 7][aRow] = a1.w;

        int col = colBase + bCol;
        const float* bp = B + (size_t)(k0 + bK) * N + col;
        if (col + 3 < N) {
            *(float4*)&sB[bK][bCol] = *(const float4*)bp;
        } else {
#pragma unroll
            for (int j = 0; j < 4; ++j)
                sB[bK][bCol + j] = (col + j < N) ? bp[j] : 0.0f;
        }
        __syncthreads();

#pragma unroll
        for (int kk = 0; kk < TK; ++kk) {
            float4 av0 = *(const float4*)&sA[kk][ty * 8];
            float4 av1 = *(const float4*)&sA[kk][ty * 8 + 4];
            float4 bv  = *(const float4*)&sB[kk][tx * 4];
            float a[8] = {av0.x, av0.y, av0.z, av0.w, av1.x, av1.y, av1.z, av1.w};
            float b[4] = {bv.x, bv.y, bv.z, bv.w};
#pragma unroll
            for (int i = 0; i < 8; ++i)
#pragma unroll
                for (int j = 0; j < 4; ++j)
                    acc[i][j] = fmaf(a[i], b[j], acc[i][j]);
        }
        __syncthreads();
    }

    int colOut = colBase + tx * 4;
    float bb[4];
#pragma unroll
    for (int j = 0; j < 4; ++j) bb[j] = (colOut + j < N) ? bias[colOut + j] : 0.0f;
#pragma unroll
    for (int i = 0; i < 8; ++i) {
        int row = rowBase + ty * 8 + i;
        if (row >= M) continue;
        float rs = rowsum ? rowsum[row] : 1.0f;
        if (colOut + 3 < N) {
            float4 v = {acc[i][0] + rs * bb[0], acc[i][1] + rs * bb[1],
                        acc[i][2] + rs * bb[2], acc[i][3] + rs * bb[3]};
            *(float4*)&C[(size_t)row * N + colOut] = v;
        } else {
#pragma unroll
            for (int j = 0; j < 4; ++j)
                if (colOut + j < N) C[(size_t)row * N + colOut + j] = acc[i][j] + rs * bb[j];
        }
    }
}

// ---------------- fp32 aggregation (layer 1): LDS-staged indices ----------------
// 256 threads = 8 slots x 32 lanes x float4, unroll x2.

__global__ __launch_bounds__(256) void aggregate128_par(
        const float* __restrict__ h, const float* __restrict__ dinv,
        const int* __restrict__ start, const int* __restrict__ indeg,
        const int* __restrict__ ssrc, float* __restrict__ out, int n, int E) {
    __shared__ int   sIdx[256];
    __shared__ float sW[256];
    __shared__ float red[8][132];
    int node = blockIdx.x;
    int tid = threadIdx.x;
    int c4 = (tid & 31) * 4;
    int slot = tid >> 5;
    float di = dinv[node];
    int s0 = start[node];
    int len = indeg[node];
    if (s0 < 0) s0 = 0;
    if (len < 0) len = 0;
    if (s0 + len > E) len = (E - s0 > 0) ? (E - s0) : 0;

    float4 acc = {0.f, 0.f, 0.f, 0.f};
    for (int chunk = 0; chunk < len; chunk += 256) {
        int m = len - chunk; if (m > 256) m = 256;
        if (tid < m) {
            int s = ssrc[s0 + chunk + tid];
            if ((unsigned)s >= (unsigned)n) { s = node; sW[tid] = 0.f; }
            else sW[tid] = dinv[s] * di;
            sIdx[tid] = s;
        }
        __syncthreads();
        int j = slot;
        for (; j + 8 < m; j += 16) {
            int sa = sIdx[j], sb = sIdx[j + 8];
            float wa = sW[j], wb = sW[j + 8];
            float4 va = *(const float4*)(h + (size_t)sa * 128 + c4);
            float4 vb = *(const float4*)(h + (size_t)sb * 128 + c4);
            acc.x = fmaf(va.x, wa, acc.x); acc.y = fmaf(va.y, wa, acc.y);
            acc.z = fmaf(va.z, wa, acc.z); acc.w = fmaf(va.w, wa, acc.w);
            acc.x = fmaf(vb.x, wb, acc.x); acc.y = fmaf(vb.y, wb, acc.y);
            acc.z = fmaf(vb.z, wb, acc.z); acc.w = fmaf(vb.w, wb, acc.w);
        }
        if (j < m) {
            int sa = sIdx[j];
            float wa = sW[j];
            float4 va = *(const float4*)(h + (size_t)sa * 128 + c4);
            acc.x = fmaf(va.x, wa, acc.x); acc.y = fmaf(va.y, wa, acc.y);
            acc.z = fmaf(va.z, wa, acc.z); acc.w = fmaf(va.w, wa, acc.w);
        }
        __syncthreads();
    }
    *(float4*)&red[slot][c4] = acc;
    __syncthreads();
    if (tid < 128) {
        int c = tid;
        float r = h[(size_t)node * 128 + c] * di * di;    // self loop
#pragma unroll
        for (int s = 0; s < 8; ++s) r += red[s][c];
        out[(size_t)node * 128 + c] = r;
    }
}

// ---------------- u8 aggregation (layers 2,3): gather 4-bit codes ----------------
// out[i][c] = sum_e (g[s]*dinv[s]*di) * q[s][c]  + di*di*g[i]*q[i][c]
// rowsum[i] = di*di + di * sum dinv[s]   (bias propagation weight)
// 256 threads = 16 slots x 16 lanes x uchar8 (128 B/row), unroll x2.

__global__ __launch_bounds__(256) void aggregate_q8(
        const unsigned char* __restrict__ q, const float* __restrict__ dinv,
        const float* __restrict__ gscale,
        const int* __restrict__ start, const int* __restrict__ indeg,
        const int* __restrict__ ssrc, float* __restrict__ out,
        float* __restrict__ rowsum, int n, int E) {
    __shared__ int   sIdx[256];
    __shared__ float sWq[256];
    __shared__ float sWb[256];
    __shared__ float red[16][132];
    int node = blockIdx.x;
    int tid = threadIdx.x;
    int lane = tid & 15;
    int slot = tid >> 4;
    int c8 = lane * 8;
    float di = dinv[node];
    int s0 = start[node];
    int len = indeg[node];
    if (s0 < 0) s0 = 0;
    if (len < 0) len = 0;
    if (s0 + len > E) len = (E - s0 > 0) ? (E - s0) : 0;

    float acc[8] = {};
    float wbpart = 0.f;
    for (int chunk = 0; chunk < len; chunk += 256) {
        int m = len - chunk; if (m > 256) m = 256;
        if (tid < m) {
            int s = ssrc[s0 + chunk + tid];
            float wq, wb;
            if ((unsigned)s >= (unsigned)n) { s = node; wq = 0.f; wb = 0.f; }
            else { wb = dinv[s] * di; wq = wb * gscale[s]; }
            sIdx[tid] = s; sWq[tid] = wq; wbpart += wb;
        }
        __syncthreads();
        int j = slot;
        for (; j + 16 < m; j += 32) {
            int sa = sIdx[j], sb = sIdx[j + 16];
            float wa = sWq[j], wb2 = sWq[j + 16];
            uint2 va = *(const uint2*)(q + (size_t)sa * 128 + c8);
            uint2 vb = *(const uint2*)(q + (size_t)sb * 128 + c8);
            acc[0] = fmaf((float)(va.x & 255), wa, acc[0]);
            acc[1] = fmaf((float)((va.x >> 8) & 255), wa, acc[1]);
            acc[2] = fmaf((float)((va.x >> 16) & 255), wa, acc[2]);
            acc[3] = fmaf((float)(va.x >> 24), wa, acc[3]);
            acc[4] = fmaf((float)(va.y & 255), wa, acc[4]);
            acc[5] = fmaf((float)((va.y >> 8) & 255), wa, acc[5]);
            acc[6] = fmaf((float)((va.y >> 16) & 255), wa, acc[6]);
            acc[7] = fmaf((float)(va.y >> 24), wa, acc[7]);
            acc[0] = fmaf((float)(vb.x & 255), wb2, acc[0]);
            acc[1] = fmaf((float)((vb.x >> 8) & 255), wb2, acc[1]);
            acc[2] = fmaf((float)((vb.x >> 16) & 255), wb2, acc[2]);
            acc[3] = fmaf((float)(vb.x >> 24), wb2, acc[3]);
            acc[4] = fmaf((float)(vb.y & 255), wb2, acc[4]);
            acc[5] = fmaf((float)((vb.y >> 8) & 255), wb2, acc[5]);
            acc[6] = fmaf((float)((vb.y >> 16) & 255), wb2, acc[6]);
            acc[7] = fmaf((float)(vb.y >> 24), wb2, acc[7]);
        }
        if (j < m) {
            int sa = sIdx[j];
            float wa = sWq[j];
            uint2 va = *(const uint2*)(q + (size_t)sa * 128 + c8);
            acc[0] = fmaf((float)(va.x & 255), wa, acc[0]);
            acc[1] = fmaf((float)((va.x >> 8) & 255), wa, acc[1]);
            acc[2] = fmaf((float)((va.x >> 16) & 255), wa, acc[2]);
            acc[3] = fmaf((float)(va.x >> 24), wa, acc[3]);
            acc[4] = fmaf((float)(va.y & 255), wa, acc[4]);
            acc[5] = fmaf((float)((va.y >> 8) & 255), wa, acc[5]);
            acc[6] = fmaf((float)((va.y >> 16) & 255), wa, acc[6]);
            acc[7] = fmaf((float)(va.y >> 24), wa, acc[7]);
        }
        __syncthreads();
    }
    *(float4*)&red[slot][c8]     = *(float4*)&acc[0];
    *(float4*)&red[slot][c8 + 4] = *(float4*)&acc[4];
    sWb[tid] = wbpart;
    __syncthreads();
    if (tid < 128) {
        int c = tid;
        float r = (float)q[(size_t)node * 128 + c] * (gscale[node] * di * di);  // self
#pragma unroll
        for (int s = 0; s < 16; ++s) r += red[s][c];
        out[(size_t)node * 128 + c] = r;
    }
    // rowsum reduction (graph-only quantity; identical on both calls)
    for (int o = 128; o; o >>= 1) {
        if (tid < o) sWb[tid] += sWb[tid + o];
        __syncthreads();
    }
    if (tid == 0) rowsum[node] = di * di + sWb[0];
}

// ---------------- BatchNorm ----------------

__global__ void bn_stats(const float* __restrict__ x, int n,
                         float* __restrict__ sums, float* __restrict__ sumsq) {
    int c = threadIdx.x;   // 128
    float s = 0.f, s2 = 0.f;
    for (int r = blockIdx.x; r < n; r += gridDim.x) {
        float v = x[(size_t)r * 128 + c];
        s += v; s2 += v * v;
    }
    atomicAdd(&sums[c], s);
    atomicAdd(&sumsq[c], s2);
}

__global__ void bn_finalize(const float* __restrict__ sums, const float* __restrict__ sumsq,
                            const float* __restrict__ g, const float* __restrict__ b,
                            int n, float* __restrict__ A, float* __restrict__ Bout) {
    int c = threadIdx.x;   // 128
    float m = sums[c] / (float)n;
    float v = sumsq[c] / (float)n - m * m;
    float a = g[c] * (1.0f / sqrtf(v + 1e-5f));
    A[c] = a;
    Bout[c] = b[c] - m * a;
}

// BN affine + ReLU + unsigned 4-bit fake-quant -> u8 code (0..15)
__global__ void bn_apply_quant_u8(const float* __restrict__ x, const float* __restrict__ A,
                                  const float* __restrict__ Bp, const float* __restrict__ gs,
                                  unsigned char* __restrict__ out, int n) {
    int idx = blockIdx.x * blockDim.x + threadIdx.x;
    if (idx >= n * 128) return;
    int c = idx & 127;
    int r = idx >> 7;
    float v = A[c] * x[idx] + Bp[c];
    v = fmaxf(v, 0.0f);
    float qv = fminf(fmaxf(v / gs[r], 0.0f), 15.0f);
    out[idx] = (unsigned char)rintf(qv);   // round-half-even
}

// ---------------- log_softmax (one wave per row) ----------------

__global__ void log_softmax_rows(const float* __restrict__ z, float* __restrict__ out,
                                 int n, int C) {
    int rowsPerBlock = blockDim.x / 64;
    int row = blockIdx.x * rowsPerBlock + (threadIdx.x / 64);
    int lane = threadIdx.x & 63;
    if (row >= n) return;
    float v = (lane < C) ? z[(size_t)row * C + lane] : -INFINITY;
    float m = v;
#pragma unroll
    for (int o = 32; o; o >>= 1) m = fmaxf(m, __shfl_xor(m, o));
    float e = (lane < C) ? expf(v - m) : 0.0f;
    float s = e;
#pragma unroll
    for (int o = 32; o; o >>= 1) s += __shfl_xor(s, o);
    if (lane < C) out[(size_t)row * C + lane] = v - m - logf(s);
}

// ---------------- launch ----------------

extern "C" void kernel_launch(void* const* d_in, const int* in_sizes, int n_in,
                              void* d_out, int out_size, void* d_ws, size_t ws_size,
                              hipStream_t stream) {
    float*       xbuf = (float*)d_in[0];          // reused as scratch after layer-1 GEMM
    const int*   ei   = (const int*)d_in[1];
    const float* W1   = (const float*)d_in[2];
    const float* b1   = (const float*)d_in[3];
    const float* a1   = (const float*)d_in[4];
    const float* W2   = (const float*)d_in[5];
    const float* b2   = (const float*)d_in[6];
    const float* a2   = (const float*)d_in[7];
    const float* g2   = (const float*)d_in[8];
    const float* W3   = (const float*)d_in[9];
    const float* b3   = (const float*)d_in[10];
    const float* a3   = (const float*)d_in[11];
    const float* g3   = (const float*)d_in[12];
    const float* bn1g = (const float*)d_in[13];
    const float* bn1b = (const float*)d_in[14];
    const float* bn2g = (const float*)d_in[15];
    const float* bn2b = (const float*)d_in[16];

    const int n = in_sizes[0] / 128;      // 50000
    const int E = in_sizes[1] / 2;        // 800000
    const int C = in_sizes[9] / 128;      // 40
    const int* src = ei;
    const int* dst = ei + E;

    // ---- workspace layout ----
    char* wsp = (char*)d_ws;
    size_t off = 0;
    auto take = [&](size_t bytes) -> void* {
        void* p = wsp + off;
        off += (bytes + 255) & ~(size_t)255;
        return p;
    };
    int*   indeg   = (int*)take((size_t)n * 4);
    int*   startA  = (int*)take((size_t)n * 4);
    int*   cursor  = (int*)take((size_t)n * 4);
    float* dinv    = (float*)take((size_t)n * 4);
    float* rowsum  = (float*)take((size_t)n * 4);
    int*   counter = (int*)take(4);
    int*   ssrc    = (int*)take((size_t)E * 4);
    float* w1q     = (float*)take(128 * 128 * 4);
    float* w2q     = (float*)take(128 * 128 * 4);
    float* w3q     = (float*)take((size_t)128 * C * 4);
    float* stats   = (float*)take(512 * 4);
    unsigned char* qbuf = (unsigned char*)take((size_t)n * 128);
    float* hbuf    = (float*)take((size_t)n * 128 * 4);

    float* sums  = stats;
    float* sumsq = stats + 128;
    float* bnA   = stats + 256;
    float* bnB   = stats + 384;
    float* outF  = (float*)d_out;

    // ---- graph structure (rebuilt every call; ws is poisoned) ----
    hipMemsetAsync(indeg, 0, (size_t)n * 4, stream);
    hipMemsetAsync(counter, 0, 4, stream);
    count_indeg<<<(E + 255) / 256, 256, 0, stream>>>(dst, E, indeg);
    compute_dinv<<<(n + 255) / 256, 256, 0, stream>>>(indeg, dinv, n);
    make_ranges<<<(n + 255) / 256, 256, 0, stream>>>(indeg, startA, cursor, counter, n);
    fill_csr<<<(E + 255) / 256, 256, 0, stream>>>(src, dst, E, cursor, ssrc);

    // ---- weight fake-quant ----
    quant_w<<<(128 * 128 + 255) / 256, 256, 0, stream>>>(W1, a1, w1q, 128 * 128);
    quant_w<<<(128 * 128 + 255) / 256, 256, 0, stream>>>(W2, a2, w2q, 128 * 128);
    quant_w<<<(128 * C + 255) / 256, 256, 0, stream>>>(W3, a3, w3q, 128 * C);

    const int nElem128 = n * 128;
    const int gElem128 = (nElem128 + 255) / 256;
    dim3 grid128((n + TM - 1) / TM, (128 + TN - 1) / TN);
    dim3 gridC((n + TM - 1) / TM, (C + TN - 1) / TN);

    // ---- layer 1 ----
    gemm_bias_tiled<<<grid128, 256, 0, stream>>>(xbuf, w1q, b1, nullptr, hbuf, n, 128, 128);
    aggregate128_par<<<n, 256, 0, stream>>>(hbuf, dinv, startA, indeg, ssrc, xbuf, n, E);
    hipMemsetAsync(stats, 0, 256 * 4, stream);
    bn_stats<<<512, 128, 0, stream>>>(xbuf, n, sums, sumsq);
    bn_finalize<<<1, 128, 0, stream>>>(sums, sumsq, bn1g, bn1b, n, bnA, bnB);
    bn_apply_quant_u8<<<gElem128, 256, 0, stream>>>(xbuf, bnA, bnB, g2, qbuf, n);

    // ---- layer 2: aggregate(q)*W + rowsum*b (linearity swap) ----
    aggregate_q8<<<n, 256, 0, stream>>>(qbuf, dinv, g2, startA, indeg, ssrc, hbuf, rowsum, n, E);
    gemm_bias_tiled<<<grid128, 256, 0, stream>>>(hbuf, w2q, b2, rowsum, xbuf, n, 128, 128);
    hipMemsetAsync(stats, 0, 256 * 4, stream);
    bn_stats<<<512, 128, 0, stream>>>(xbuf, n, sums, sumsq);
    bn_finalize<<<1, 128, 0, stream>>>(sums, sumsq, bn2g, bn2b, n, bnA, bnB);
    bn_apply_quant_u8<<<gElem128, 256, 0, stream>>>(xbuf, bnA, bnB, g3, qbuf, n);

    // ---- layer 3: aggregate(q)*W3 + rowsum*b3, then log_softmax ----
    aggregate_q8<<<n, 256, 0, stream>>>(qbuf, dinv, g3, startA, indeg, ssrc, hbuf, rowsum, n, E);
    gemm_bias_tiled<<<gridC, 256, 0, stream>>>(hbuf, w3q, b3, rowsum, xbuf, n, C, 128);
    log_softmax_rows<<<(n + 3) / 4, 256, 0, stream>>>(xbuf, outF, n, C);
}

// Round 7
// 564.729 us; speedup vs baseline: 1.0759x; 1.0759x over previous
//
#include <hip/hip_runtime.h>
#include <hip/hip_bf16.h>
#include <math.h>

// ---------------- graph structure ----------------

__global__ void count_indeg(const int* __restrict__ dst, int e, int* __restrict__ indeg) {
    int i = blockIdx.x * blockDim.x + threadIdx.x;
    if (i < e) atomicAdd(&indeg[dst[i]], 1);
}

__global__ void compute_dinv(const int* __restrict__ indeg, float* __restrict__ dinv, int n) {
    int i = blockIdx.x * blockDim.x + threadIdx.x;
    if (i < n) {
        float deg = (float)(indeg[i] + 1);   // + self loop, always >= 1
        dinv[i] = 1.0f / sqrtf(deg);
    }
}

__global__ void make_ranges(const int* __restrict__ indeg, int* __restrict__ start,
                            int* __restrict__ cursor, int* __restrict__ counter, int n) {
    int i = blockIdx.x * blockDim.x + threadIdx.x;
    if (i < n) {
        int s = atomicAdd(counter, indeg[i]);
        start[i] = s;
        cursor[i] = s;
    }
}

__global__ void fill_csr(const int* __restrict__ src, const int* __restrict__ dst, int e,
                         int* __restrict__ cursor, int* __restrict__ ssrc) {
    int i = blockIdx.x * blockDim.x + threadIdx.x;
    if (i < e) {
        int p = atomicAdd(&cursor[dst[i]], 1);
        if (p >= 0 && p < e) ssrc[p] = src[i];
    }
}

// ---------------- weight fake-quant (symmetric 4-bit) ----------------

__global__ void quant_w(const float* __restrict__ w, const float* __restrict__ a,
                        float* __restrict__ wq, int n) {
    int i = blockIdx.x * blockDim.x + threadIdx.x;
    if (i < n) {
        float s = a[0];
        float v = w[i] / s;
        v = fminf(fmaxf(v, -8.0f), 7.0f);
        wq[i] = rintf(v) * s;   // round-half-even, matches jnp.round
    }
}

// ---------------- tiled GEMM: C[M,N] = A[M,K] @ B[K,N] + rs[row]*bias[N] ----------------

#define TM 128
#define TN 64
#define TK 16

__global__ __launch_bounds__(256) void gemm_bias_tiled(
        const float* __restrict__ A, const float* __restrict__ B,
        const float* __restrict__ bias, const float* __restrict__ rowsum,
        float* __restrict__ C, int M, int N, int K) {
    __shared__ float sA[TK][TM + 4];
    __shared__ float sB[TK][TN + 4];
    int tid = threadIdx.x;
    int rowBase = blockIdx.x * TM;
    int colBase = blockIdx.y * TN;
    int tx = tid & 15;
    int ty = tid >> 4;
    float acc[8][4] = {};

    int aRow = tid >> 1;
    int aK   = (tid & 1) * 8;
    int bK   = tid >> 4;
    int bCol = (tid & 15) * 4;

    for (int k0 = 0; k0 < K; k0 += TK) {
        int gRow = rowBase + aRow;
        if (gRow >= M) gRow = M - 1;            // clamp; discarded at store
        const float* ap = A + (size_t)gRow * K + k0 + aK;
        float4 a0 = *(const float4*)ap;
        float4 a1 = *(const float4*)(ap + 4);
        sA[aK + 0][aRow] = a0.x;
        sA[aK + 1][aRow] = a0.y;
        sA[aK + 2][aRow] = a0.z;
        sA[aK + 3][aRow] = a0.w;
        sA[aK + 4][aRow] = a1.x;
        sA[aK + 5][aRow] = a1.y;
        sA[aK + 6][aRow] = a1.z;
        sA[aK + 7][aRow] = a1.w;

        int col = colBase + bCol;
        const float* bp = B + (size_t)(k0 + bK) * N + col;
        if (col + 3 < N) {
            *(float4*)&sB[bK][bCol] = *(const float4*)bp;
        } else {
#pragma unroll
            for (int j = 0; j < 4; ++j)
                sB[bK][bCol + j] = (col + j < N) ? bp[j] : 0.0f;
        }
        __syncthreads();

#pragma unroll
        for (int kk = 0; kk < TK; ++kk) {
            float4 av0 = *(const float4*)&sA[kk][ty * 8];
            float4 av1 = *(const float4*)&sA[kk][ty * 8 + 4];
            float4 bv  = *(const float4*)&sB[kk][tx * 4];
            float a[8] = {av0.x, av0.y, av0.z, av0.w, av1.x, av1.y, av1.z, av1.w};
            float b[4] = {bv.x, bv.y, bv.z, bv.w};
#pragma unroll
            for (int i = 0; i < 8; ++i)
#pragma unroll
                for (int j = 0; j < 4; ++j)
                    acc[i][j] = fmaf(a[i], b[j], acc[i][j]);
        }
        __syncthreads();
    }

    int colOut = colBase + tx * 4;
    float bb[4];
#pragma unroll
    for (int j = 0; j < 4; ++j) bb[j] = (colOut + j < N) ? bias[colOut + j] : 0.0f;
#pragma unroll
    for (int i = 0; i < 8; ++i) {
        int row = rowBase + ty * 8 + i;
        if (row >= M) continue;
        float rs = rowsum ? rowsum[row] : 1.0f;
        if (colOut + 3 < N) {
            float4 v = {acc[i][0] + rs * bb[0], acc[i][1] + rs * bb[1],
                        acc[i][2] + rs * bb[2], acc[i][3] + rs * bb[3]};
            *(float4*)&C[(size_t)row * N + colOut] = v;
        } else {
#pragma unroll
            for (int j = 0; j < 4; ++j)
                if (colOut + j < N) C[(size_t)row * N + colOut + j] = acc[i][j] + rs * bb[j];
        }
    }
}

// ---------------- fp32 aggregation (layer 1): one WAVE per node ----------------
// 64 lanes x float2 = one 512B row per gather; edges unrolled x4; no LDS, no barriers.

__global__ __launch_bounds__(256) void aggregate_f32_wave(
        const float* __restrict__ h, const float* __restrict__ dinv,
        const int* __restrict__ start, const int* __restrict__ indeg,
        const int* __restrict__ ssrc, float* __restrict__ out, int n, int E) {
    int node = blockIdx.x * 4 + (threadIdx.x >> 6);
    if (node >= n) return;
    int lane = threadIdx.x & 63;
    int c2 = lane * 2;
    float di = dinv[node];
    int s0 = start[node];
    int len = indeg[node];
    if (s0 < 0) s0 = 0;
    if (len < 0) len = 0;
    if (s0 + len > E) len = (E - s0 > 0) ? (E - s0) : 0;

    float ax = 0.f, ay = 0.f;
    int j = 0;
    for (; j + 3 < len; j += 4) {
        int sa = ssrc[s0 + j];       // same addr across wave -> broadcast
        int sb = ssrc[s0 + j + 1];
        int sc = ssrc[s0 + j + 2];
        int sd = ssrc[s0 + j + 3];
        float wa = ((unsigned)sa < (unsigned)n) ? dinv[sa] * di : 0.f; if ((unsigned)sa >= (unsigned)n) sa = node;
        float wb = ((unsigned)sb < (unsigned)n) ? dinv[sb] * di : 0.f; if ((unsigned)sb >= (unsigned)n) sb = node;
        float wc = ((unsigned)sc < (unsigned)n) ? dinv[sc] * di : 0.f; if ((unsigned)sc >= (unsigned)n) sc = node;
        float wd = ((unsigned)sd < (unsigned)n) ? dinv[sd] * di : 0.f; if ((unsigned)sd >= (unsigned)n) sd = node;
        float2 va = *(const float2*)(h + (size_t)sa * 128 + c2);
        float2 vb = *(const float2*)(h + (size_t)sb * 128 + c2);
        float2 vc = *(const float2*)(h + (size_t)sc * 128 + c2);
        float2 vd = *(const float2*)(h + (size_t)sd * 128 + c2);
        ax = fmaf(va.x, wa, ax); ay = fmaf(va.y, wa, ay);
        ax = fmaf(vb.x, wb, ax); ay = fmaf(vb.y, wb, ay);
        ax = fmaf(vc.x, wc, ax); ay = fmaf(vc.y, wc, ay);
        ax = fmaf(vd.x, wd, ax); ay = fmaf(vd.y, wd, ay);
    }
    for (; j < len; ++j) {
        int sa = ssrc[s0 + j];
        float wa = ((unsigned)sa < (unsigned)n) ? dinv[sa] * di : 0.f; if ((unsigned)sa >= (unsigned)n) sa = node;
        float2 va = *(const float2*)(h + (size_t)sa * 128 + c2);
        ax = fmaf(va.x, wa, ax); ay = fmaf(va.y, wa, ay);
    }
    float2 self = *(const float2*)(h + (size_t)node * 128 + c2);
    float dd = di * di;
    float2 o = {fmaf(self.x, dd, ax), fmaf(self.y, dd, ay)};
    *(float2*)(out + (size_t)node * 128 + c2) = o;
}

// ---------------- u8 aggregation (layers 2,3): one WAVE per node ----------------
// 8 slots x 8 lanes x uint4 (one 128B row per slot), unroll x2 -> 16 rows in flight/wave.
// Cross-slot reduce + rowsum via shuffles. No LDS, no barriers.

__device__ __forceinline__ void unpack_fma(float* acc, uint4 v, float w) {
    acc[0]  = fmaf((float)(v.x & 255), w, acc[0]);
    acc[1]  = fmaf((float)((v.x >> 8) & 255), w, acc[1]);
    acc[2]  = fmaf((float)((v.x >> 16) & 255), w, acc[2]);
    acc[3]  = fmaf((float)(v.x >> 24), w, acc[3]);
    acc[4]  = fmaf((float)(v.y & 255), w, acc[4]);
    acc[5]  = fmaf((float)((v.y >> 8) & 255), w, acc[5]);
    acc[6]  = fmaf((float)((v.y >> 16) & 255), w, acc[6]);
    acc[7]  = fmaf((float)(v.y >> 24), w, acc[7]);
    acc[8]  = fmaf((float)(v.z & 255), w, acc[8]);
    acc[9]  = fmaf((float)((v.z >> 8) & 255), w, acc[9]);
    acc[10] = fmaf((float)((v.z >> 16) & 255), w, acc[10]);
    acc[11] = fmaf((float)(v.z >> 24), w, acc[11]);
    acc[12] = fmaf((float)(v.w & 255), w, acc[12]);
    acc[13] = fmaf((float)((v.w >> 8) & 255), w, acc[13]);
    acc[14] = fmaf((float)((v.w >> 16) & 255), w, acc[14]);
    acc[15] = fmaf((float)(v.w >> 24), w, acc[15]);
}

__global__ __launch_bounds__(256) void aggregate_q8_wave(
        const unsigned char* __restrict__ q, const float* __restrict__ dinv,
        const float* __restrict__ gscale,
        const int* __restrict__ start, const int* __restrict__ indeg,
        const int* __restrict__ ssrc, float* __restrict__ out,
        float* __restrict__ rowsum, int n, int E) {
    int node = blockIdx.x * 4 + (threadIdx.x >> 6);
    if (node >= n) return;
    int lane = threadIdx.x & 63;
    int slot = lane >> 3;      // 0..7
    int sl   = lane & 7;       // lane in slot; covers bytes sl*16..sl*16+15
    float di = dinv[node];
    int s0 = start[node];
    int len = indeg[node];
    if (s0 < 0) s0 = 0;
    if (len < 0) len = 0;
    if (s0 + len > E) len = (E - s0 > 0) ? (E - s0) : 0;

    float acc[16] = {};
    float wbsum = 0.f;
    int j = slot;
    for (; j + 8 < len; j += 16) {
        int sa = ssrc[s0 + j];          // broadcast within slot
        int sb = ssrc[s0 + j + 8];
        float wqa, wba, wqb, wbb;
        if ((unsigned)sa >= (unsigned)n) { sa = node; wqa = 0.f; wba = 0.f; }
        else { wba = dinv[sa] * di; wqa = wba * gscale[sa]; }
        if ((unsigned)sb >= (unsigned)n) { sb = node; wqb = 0.f; wbb = 0.f; }
        else { wbb = dinv[sb] * di; wqb = wbb * gscale[sb]; }
        if (sl == 0) wbsum += wba + wbb;
        uint4 va = *(const uint4*)(q + (size_t)sa * 128 + sl * 16);
        uint4 vb = *(const uint4*)(q + (size_t)sb * 128 + sl * 16);
        unpack_fma(acc, va, wqa);
        unpack_fma(acc, vb, wqb);
    }
    if (j < len) {
        int sa = ssrc[s0 + j];
        float wqa, wba;
        if ((unsigned)sa >= (unsigned)n) { sa = node; wqa = 0.f; wba = 0.f; }
        else { wba = dinv[sa] * di; wqa = wba * gscale[sa]; }
        if (sl == 0) wbsum += wba;
        uint4 va = *(const uint4*)(q + (size_t)sa * 128 + sl * 16);
        unpack_fma(acc, va, wqa);
    }
    // reduce across slots (lanes differing in bits 3..5, same sl)
#pragma unroll
    for (int o = 8; o < 64; o <<= 1) {
#pragma unroll
        for (int k = 0; k < 16; ++k) acc[k] += __shfl_xor(acc[k], o);
    }
    // rowsum: only sl==0 lanes contributed; full butterfly
#pragma unroll
    for (int o = 1; o < 64; o <<= 1) wbsum += __shfl_xor(wbsum, o);
    if (lane == 0) rowsum[node] = di * di + wbsum;
    // self-loop + store: slot 0 (lanes 0..7), each writes 16 channels
    if (slot == 0) {
        uint4 vs = *(const uint4*)(q + (size_t)node * 128 + sl * 16);
        unpack_fma(acc, vs, gscale[node] * di * di);
        float* op = out + (size_t)node * 128 + sl * 16;
        *(float4*)(op + 0)  = *(float4*)&acc[0];
        *(float4*)(op + 4)  = *(float4*)&acc[4];
        *(float4*)(op + 8)  = *(float4*)&acc[8];
        *(float4*)(op + 12) = *(float4*)&acc[12];
    }
}

// ---------------- BatchNorm ----------------

__global__ void bn_stats(const float* __restrict__ x, int n,
                         float* __restrict__ sums, float* __restrict__ sumsq) {
    int c = threadIdx.x;   // 128
    float s = 0.f, s2 = 0.f;
    for (int r = blockIdx.x; r < n; r += gridDim.x) {
        float v = x[(size_t)r * 128 + c];
        s += v; s2 += v * v;
    }
    atomicAdd(&sums[c], s);
    atomicAdd(&sumsq[c], s2);
}

__global__ void bn_finalize(const float* __restrict__ sums, const float* __restrict__ sumsq,
                            const float* __restrict__ g, const float* __restrict__ b,
                            int n, float* __restrict__ A, float* __restrict__ Bout) {
    int c = threadIdx.x;   // 128
    float m = sums[c] / (float)n;
    float v = sumsq[c] / (float)n - m * m;
    float a = g[c] * (1.0f / sqrtf(v + 1e-5f));
    A[c] = a;
    Bout[c] = b[c] - m * a;
}

// BN affine + ReLU + unsigned 4-bit fake-quant -> u8 code (0..15)
__global__ void bn_apply_quant_u8(const float* __restrict__ x, const float* __restrict__ A,
                                  const float* __restrict__ Bp, const float* __restrict__ gs,
                                  unsigned char* __restrict__ out, int n) {
    int idx = blockIdx.x * blockDim.x + threadIdx.x;
    if (idx >= n * 128) return;
    int c = idx & 127;
    int r = idx >> 7;
    float v = A[c] * x[idx] + Bp[c];
    v = fmaxf(v, 0.0f);
    float qv = fminf(fmaxf(v / gs[r], 0.0f), 15.0f);
    out[idx] = (unsigned char)rintf(qv);   // round-half-even
}

// ---------------- log_softmax (one wave per row) ----------------

__global__ void log_softmax_rows(const float* __restrict__ z, float* __restrict__ out,
                                 int n, int C) {
    int rowsPerBlock = blockDim.x / 64;
    int row = blockIdx.x * rowsPerBlock + (threadIdx.x / 64);
    int lane = threadIdx.x & 63;
    if (row >= n) return;
    float v = (lane < C) ? z[(size_t)row * C + lane] : -INFINITY;
    float m = v;
#pragma unroll
    for (int o = 32; o; o >>= 1) m = fmaxf(m, __shfl_xor(m, o));
    float e = (lane < C) ? expf(v - m) : 0.0f;
    float s = e;
#pragma unroll
    for (int o = 32; o; o >>= 1) s += __shfl_xor(s, o);
    if (lane < C) out[(size_t)row * C + lane] = v - m - logf(s);
}

// ---------------- launch ----------------

extern "C" void kernel_launch(void* const* d_in, const int* in_sizes, int n_in,
                              void* d_out, int out_size, void* d_ws, size_t ws_size,
                              hipStream_t stream) {
    float*       xbuf = (float*)d_in[0];          // reused as scratch after layer-1 GEMM
    const int*   ei   = (const int*)d_in[1];
    const float* W1   = (const float*)d_in[2];
    const float* b1   = (const float*)d_in[3];
    const float* a1   = (const float*)d_in[4];
    const float* W2   = (const float*)d_in[5];
    const float* b2   = (const float*)d_in[6];
    const float* a2   = (const float*)d_in[7];
    const float* g2   = (const float*)d_in[8];
    const float* W3   = (const float*)d_in[9];
    const float* b3   = (const float*)d_in[10];
    const float* a3   = (const float*)d_in[11];
    const float* g3   = (const float*)d_in[12];
    const float* bn1g = (const float*)d_in[13];
    const float* bn1b = (const float*)d_in[14];
    const float* bn2g = (const float*)d_in[15];
    const float* bn2b = (const float*)d_in[16];

    const int n = in_sizes[0] / 128;      // 50000
    const int E = in_sizes[1] / 2;        // 800000
    const int C = in_sizes[9] / 128;      // 40
    const int* src = ei;
    const int* dst = ei + E;

    // ---- workspace layout ----
    char* wsp = (char*)d_ws;
    size_t off = 0;
    auto take = [&](size_t bytes) -> void* {
        void* p = wsp + off;
        off += (bytes + 255) & ~(size_t)255;
        return p;
    };
    int*   indeg   = (int*)take((size_t)n * 4);
    int*   startA  = (int*)take((size_t)n * 4);
    int*   cursor  = (int*)take((size_t)n * 4);
    float* dinv    = (float*)take((size_t)n * 4);
    float* rowsum  = (float*)take((size_t)n * 4);
    int*   counter = (int*)take(4);
    int*   ssrc    = (int*)take((size_t)E * 4);
    float* w1q     = (float*)take(128 * 128 * 4);
    float* w2q     = (float*)take(128 * 128 * 4);
    float* w3q     = (float*)take((size_t)128 * C * 4);
    float* stats   = (float*)take(512 * 4);
    unsigned char* qbuf = (unsigned char*)take((size_t)n * 128);
    float* hbuf    = (float*)take((size_t)n * 128 * 4);

    float* sums  = stats;
    float* sumsq = stats + 128;
    float* bnA   = stats + 256;
    float* bnB   = stats + 384;
    float* outF  = (float*)d_out;

    // ---- graph structure (rebuilt every call; ws is poisoned) ----
    hipMemsetAsync(indeg, 0, (size_t)n * 4, stream);
    hipMemsetAsync(counter, 0, 4, stream);
    count_indeg<<<(E + 255) / 256, 256, 0, stream>>>(dst, E, indeg);
    compute_dinv<<<(n + 255) / 256, 256, 0, stream>>>(indeg, dinv, n);
    make_ranges<<<(n + 255) / 256, 256, 0, stream>>>(indeg, startA, cursor, counter, n);
    fill_csr<<<(E + 255) / 256, 256, 0, stream>>>(src, dst, E, cursor, ssrc);

    // ---- weight fake-quant ----
    quant_w<<<(128 * 128 + 255) / 256, 256, 0, stream>>>(W1, a1, w1q, 128 * 128);
    quant_w<<<(128 * 128 + 255) / 256, 256, 0, stream>>>(W2, a2, w2q, 128 * 128);
    quant_w<<<(128 * C + 255) / 256, 256, 0, stream>>>(W3, a3, w3q, 128 * C);

    const int nElem128 = n * 128;
    const int gElem128 = (nElem128 + 255) / 256;
    const int gWave = (n + 3) / 4;        // 4 waves of work per 256-block
    dim3 grid128((n + TM - 1) / TM, (128 + TN - 1) / TN);
    dim3 gridC((n + TM - 1) / TM, (C + TN - 1) / TN);

    // ---- layer 1 ----
    gemm_bias_tiled<<<grid128, 256, 0, stream>>>(xbuf, w1q, b1, nullptr, hbuf, n, 128, 128);
    aggregate_f32_wave<<<gWave, 256, 0, stream>>>(hbuf, dinv, startA, indeg, ssrc, xbuf, n, E);
    hipMemsetAsync(stats, 0, 256 * 4, stream);
    bn_stats<<<512, 128, 0, stream>>>(xbuf, n, sums, sumsq);
    bn_finalize<<<1, 128, 0, stream>>>(sums, sumsq, bn1g, bn1b, n, bnA, bnB);
    bn_apply_quant_u8<<<gElem128, 256, 0, stream>>>(xbuf, bnA, bnB, g2, qbuf, n);

    // ---- layer 2: aggregate(q)*W + rowsum*b (linearity swap) ----
    aggregate_q8_wave<<<gWave, 256, 0, stream>>>(qbuf, dinv, g2, startA, indeg, ssrc, hbuf, rowsum, n, E);
    gemm_bias_tiled<<<grid128, 256, 0, stream>>>(hbuf, w2q, b2, rowsum, xbuf, n, 128, 128);
    hipMemsetAsync(stats, 0, 256 * 4, stream);
    bn_stats<<<512, 128, 0, stream>>>(xbuf, n, sums, sumsq);
    bn_finalize<<<1, 128, 0, stream>>>(sums, sumsq, bn2g, bn2b, n, bnA, bnB);
    bn_apply_quant_u8<<<gElem128, 256, 0, stream>>>(xbuf, bnA, bnB, g3, qbuf, n);

    // ---- layer 3: aggregate(q)*W3 + rowsum*b3, then log_softmax ----
    aggregate_q8_wave<<<gWave, 256, 0, stream>>>(qbuf, dinv, g3, startA, indeg, ssrc, hbuf, rowsum, n, E);
    gemm_bias_tiled<<<gridC, 256, 0, stream>>>(hbuf, w3q, b3, rowsum, xbuf, n, C, 128);
    log_softmax_rows<<<(n + 3) / 4, 256, 0, stream>>>(xbuf, outF, n, C);
}

// Round 8
// 530.595 us; speedup vs baseline: 1.1451x; 1.0643x over previous
//
#include <hip/hip_runtime.h>
#include <hip/hip_bf16.h>
#include <math.h>

// ---------------- graph structure ----------------

__global__ void count_indeg(const int* __restrict__ dst, int e, int* __restrict__ indeg) {
    int i = blockIdx.x * blockDim.x + threadIdx.x;
    if (i < e) atomicAdd(&indeg[dst[i]], 1);
}

// fused: dinv + disjoint range assignment
__global__ void dinv_ranges(const int* __restrict__ indeg, float* __restrict__ dinv,
                            int* __restrict__ start, int* __restrict__ cursor,
                            int* __restrict__ counter, int n) {
    int i = blockIdx.x * blockDim.x + threadIdx.x;
    if (i < n) {
        int d = indeg[i];
        dinv[i] = 1.0f / sqrtf((float)(d + 1));
        int s = atomicAdd(counter, d);
        start[i] = s;
        cursor[i] = s;
    }
}

__global__ void fill_csr(const int* __restrict__ src, const int* __restrict__ dst, int e,
                         int* __restrict__ cursor, int* __restrict__ ssrc) {
    int i = blockIdx.x * blockDim.x + threadIdx.x;
    if (i < e) {
        int p = atomicAdd(&cursor[dst[i]], 1);
        if (p >= 0 && p < e) ssrc[p] = src[i];
    }
}

// ---------------- fused weight fake-quant (all three matrices) ----------------

__global__ void quant_w_all(const float* __restrict__ W1, const float* __restrict__ a1,
                            const float* __restrict__ W2, const float* __restrict__ a2,
                            const float* __restrict__ W3, const float* __restrict__ a3,
                            float* __restrict__ w1q, float* __restrict__ w2q,
                            float* __restrict__ w3q, int n1, int n2, int n3) {
    int i = blockIdx.x * blockDim.x + threadIdx.x;
    const float* w; const float* a; float* o; int k;
    if (i < n1) { w = W1; a = a1; o = w1q; k = i; }
    else if (i < n1 + n2) { w = W2; a = a2; o = w2q; k = i - n1; }
    else if (i < n1 + n2 + n3) { w = W3; a = a3; o = w3q; k = i - n1 - n2; }
    else return;
    float s = a[0];
    float v = w[k] / s;
    v = fminf(fmaxf(v, -8.0f), 7.0f);
    o[k] = rintf(v) * s;   // round-half-even, matches jnp.round
}

// ---------------- tiled GEMM: C[M,N] = A[M,K] @ B[K,N] + rs[row]*bias[N] ----------------

#define TM 128
#define TN 64
#define TK 16

__global__ __launch_bounds__(256) void gemm_bias_tiled(
        const float* __restrict__ A, const float* __restrict__ B,
        const float* __restrict__ bias, const float* __restrict__ rowsum,
        float* __restrict__ C, int M, int N, int K) {
    __shared__ float sA[TK][TM + 4];
    __shared__ float sB[TK][TN + 4];
    int tid = threadIdx.x;
    int rowBase = blockIdx.x * TM;
    int colBase = blockIdx.y * TN;
    int tx = tid & 15;
    int ty = tid >> 4;
    float acc[8][4] = {};

    int aRow = tid >> 1;
    int aK   = (tid & 1) * 8;
    int bK   = tid >> 4;
    int bCol = (tid & 15) * 4;

    for (int k0 = 0; k0 < K; k0 += TK) {
        int gRow = rowBase + aRow;
        if (gRow >= M) gRow = M - 1;            // clamp; discarded at store
        const float* ap = A + (size_t)gRow * K + k0 + aK;
        float4 a0 = *(const float4*)ap;
        float4 a1 = *(const float4*)(ap + 4);
        sA[aK + 0][aRow] = a0.x;
        sA[aK + 1][aRow] = a0.y;
        sA[aK + 2][aRow] = a0.z;
        sA[aK + 3][aRow] = a0.w;
        sA[aK + 4][aRow] = a1.x;
        sA[aK + 5][aRow] = a1.y;
        sA[aK + 6][aRow] = a1.z;
        sA[aK + 7][aRow] = a1.w;

        int col = colBase + bCol;
        const float* bp = B + (size_t)(k0 + bK) * N + col;
        if (col + 3 < N) {
            *(float4*)&sB[bK][bCol] = *(const float4*)bp;
        } else {
#pragma unroll
            for (int j = 0; j < 4; ++j)
                sB[bK][bCol + j] = (col + j < N) ? bp[j] : 0.0f;
        }
        __syncthreads();

#pragma unroll
        for (int kk = 0; kk < TK; ++kk) {
            float4 av0 = *(const float4*)&sA[kk][ty * 8];
            float4 av1 = *(const float4*)&sA[kk][ty * 8 + 4];
            float4 bv  = *(const float4*)&sB[kk][tx * 4];
            float a[8] = {av0.x, av0.y, av0.z, av0.w, av1.x, av1.y, av1.z, av1.w};
            float b[4] = {bv.x, bv.y, bv.z, bv.w};
#pragma unroll
            for (int i = 0; i < 8; ++i)
#pragma unroll
                for (int j = 0; j < 4; ++j)
                    acc[i][j] = fmaf(a[i], b[j], acc[i][j]);
        }
        __syncthreads();
    }

    int colOut = colBase + tx * 4;
    float bb[4];
#pragma unroll
    for (int j = 0; j < 4; ++j) bb[j] = (colOut + j < N) ? bias[colOut + j] : 0.0f;
#pragma unroll
    for (int i = 0; i < 8; ++i) {
        int row = rowBase + ty * 8 + i;
        if (row >= M) continue;
        float rs = rowsum ? rowsum[row] : 1.0f;
        if (colOut + 3 < N) {
            float4 v = {acc[i][0] + rs * bb[0], acc[i][1] + rs * bb[1],
                        acc[i][2] + rs * bb[2], acc[i][3] + rs * bb[3]};
            *(float4*)&C[(size_t)row * N + colOut] = v;
        } else {
#pragma unroll
            for (int j = 0; j < 4; ++j)
                if (colOut + j < N) C[(size_t)row * N + colOut + j] = acc[i][j] + rs * bb[j];
        }
    }
}

// ---------------- fp32 aggregation (layer 1): block per node, LDS-staged indices ----------------
// 256 threads = 8 slots x 32 lanes x float4, unroll x2. (round-5 structure, padded reduce)

__global__ __launch_bounds__(256) void aggregate128_par(
        const float* __restrict__ h, const float* __restrict__ dinv,
        const int* __restrict__ start, const int* __restrict__ indeg,
        const int* __restrict__ ssrc, float* __restrict__ out, int n, int E) {
    __shared__ int   sIdx[256];
    __shared__ float sW[256];
    __shared__ float red[8][132];
    int node = blockIdx.x;
    int tid = threadIdx.x;
    int c4 = (tid & 31) * 4;
    int slot = tid >> 5;
    float di = dinv[node];
    int s0 = start[node];
    int len = indeg[node];
    if (s0 < 0) s0 = 0;
    if (len < 0) len = 0;
    if (s0 + len > E) len = (E - s0 > 0) ? (E - s0) : 0;

    float4 acc = {0.f, 0.f, 0.f, 0.f};
    for (int chunk = 0; chunk < len; chunk += 256) {
        int m = len - chunk; if (m > 256) m = 256;
        if (tid < m) {
            int s = ssrc[s0 + chunk + tid];
            if ((unsigned)s >= (unsigned)n) { s = node; sW[tid] = 0.f; }
            else sW[tid] = dinv[s] * di;
            sIdx[tid] = s;
        }
        __syncthreads();
        int j = slot;
        for (; j + 8 < m; j += 16) {
            int sa = sIdx[j], sb = sIdx[j + 8];
            float wa = sW[j], wb = sW[j + 8];
            float4 va = *(const float4*)(h + (size_t)sa * 128 + c4);
            float4 vb = *(const float4*)(h + (size_t)sb * 128 + c4);
            acc.x = fmaf(va.x, wa, acc.x); acc.y = fmaf(va.y, wa, acc.y);
            acc.z = fmaf(va.z, wa, acc.z); acc.w = fmaf(va.w, wa, acc.w);
            acc.x = fmaf(vb.x, wb, acc.x); acc.y = fmaf(vb.y, wb, acc.y);
            acc.z = fmaf(vb.z, wb, acc.z); acc.w = fmaf(vb.w, wb, acc.w);
        }
        if (j < m) {
            int sa = sIdx[j];
            float wa = sW[j];
            float4 va = *(const float4*)(h + (size_t)sa * 128 + c4);
            acc.x = fmaf(va.x, wa, acc.x); acc.y = fmaf(va.y, wa, acc.y);
            acc.z = fmaf(va.z, wa, acc.z); acc.w = fmaf(va.w, wa, acc.w);
        }
        __syncthreads();
    }
    *(float4*)&red[slot][c4] = acc;
    __syncthreads();
    if (tid < 128) {
        int c = tid;
        float r = h[(size_t)node * 128 + c] * di * di;    // self loop
#pragma unroll
        for (int s = 0; s < 8; ++s) r += red[s][c];       // pad 132: conflict-free
        out[(size_t)node * 128 + c] = r;
    }
}

// ---------------- u8 aggregation (layers 2,3): one WAVE per node ----------------
// 8 slots x 8 lanes x uint4 (one 128B row per slot), unroll x2. Shuffle reductions only.

__device__ __forceinline__ void unpack_fma(float* acc, uint4 v, float w) {
    acc[0]  = fmaf((float)(v.x & 255), w, acc[0]);
    acc[1]  = fmaf((float)((v.x >> 8) & 255), w, acc[1]);
    acc[2]  = fmaf((float)((v.x >> 16) & 255), w, acc[2]);
    acc[3]  = fmaf((float)(v.x >> 24), w, acc[3]);
    acc[4]  = fmaf((float)(v.y & 255), w, acc[4]);
    acc[5]  = fmaf((float)((v.y >> 8) & 255), w, acc[5]);
    acc[6]  = fmaf((float)((v.y >> 16) & 255), w, acc[6]);
    acc[7]  = fmaf((float)(v.y >> 24), w, acc[7]);
    acc[8]  = fmaf((float)(v.z & 255), w, acc[8]);
    acc[9]  = fmaf((float)((v.z >> 8) & 255), w, acc[9]);
    acc[10] = fmaf((float)((v.z >> 16) & 255), w, acc[10]);
    acc[11] = fmaf((float)(v.z >> 24), w, acc[11]);
    acc[12] = fmaf((float)(v.w & 255), w, acc[12]);
    acc[13] = fmaf((float)((v.w >> 8) & 255), w, acc[13]);
    acc[14] = fmaf((float)((v.w >> 16) & 255), w, acc[14]);
    acc[15] = fmaf((float)(v.w >> 24), w, acc[15]);
}

__global__ __launch_bounds__(256) void aggregate_q8_wave(
        const unsigned char* __restrict__ q, const float* __restrict__ dinv,
        const float* __restrict__ gscale,
        const int* __restrict__ start, const int* __restrict__ indeg,
        const int* __restrict__ ssrc, float* __restrict__ out,
        float* __restrict__ rowsum, int n, int E) {
    int node = blockIdx.x * 4 + (threadIdx.x >> 6);
    if (node >= n) return;
    int lane = threadIdx.x & 63;
    int slot = lane >> 3;      // 0..7
    int sl   = lane & 7;       // covers bytes sl*16..sl*16+15
    float di = dinv[node];
    int s0 = start[node];
    int len = indeg[node];
    if (s0 < 0) s0 = 0;
    if (len < 0) len = 0;
    if (s0 + len > E) len = (E - s0 > 0) ? (E - s0) : 0;

    float acc[16] = {};
    float wbsum = 0.f;
    int j = slot;
    for (; j + 8 < len; j += 16) {
        int sa = ssrc[s0 + j];
        int sb = ssrc[s0 + j + 8];
        float wqa, wba, wqb, wbb;
        if ((unsigned)sa >= (unsigned)n) { sa = node; wqa = 0.f; wba = 0.f; }
        else { wba = dinv[sa] * di; wqa = wba * gscale[sa]; }
        if ((unsigned)sb >= (unsigned)n) { sb = node; wqb = 0.f; wbb = 0.f; }
        else { wbb = dinv[sb] * di; wqb = wbb * gscale[sb]; }
        if (sl == 0) wbsum += wba + wbb;
        uint4 va = *(const uint4*)(q + (size_t)sa * 128 + sl * 16);
        uint4 vb = *(const uint4*)(q + (size_t)sb * 128 + sl * 16);
        unpack_fma(acc, va, wqa);
        unpack_fma(acc, vb, wqb);
    }
    if (j < len) {
        int sa = ssrc[s0 + j];
        float wqa, wba;
        if ((unsigned)sa >= (unsigned)n) { sa = node; wqa = 0.f; wba = 0.f; }
        else { wba = dinv[sa] * di; wqa = wba * gscale[sa]; }
        if (sl == 0) wbsum += wba;
        uint4 va = *(const uint4*)(q + (size_t)sa * 128 + sl * 16);
        unpack_fma(acc, va, wqa);
    }
#pragma unroll
    for (int o = 8; o < 64; o <<= 1) {
#pragma unroll
        for (int k = 0; k < 16; ++k) acc[k] += __shfl_xor(acc[k], o);
    }
#pragma unroll
    for (int o = 1; o < 64; o <<= 1) wbsum += __shfl_xor(wbsum, o);
    if (lane == 0) rowsum[node] = di * di + wbsum;
    if (slot == 0) {
        uint4 vs = *(const uint4*)(q + (size_t)node * 128 + sl * 16);
        unpack_fma(acc, vs, gscale[node] * di * di);
        float* op = out + (size_t)node * 128 + sl * 16;
        *(float4*)(op + 0)  = *(float4*)&acc[0];
        *(float4*)(op + 4)  = *(float4*)&acc[4];
        *(float4*)(op + 8)  = *(float4*)&acc[8];
        *(float4*)(op + 12) = *(float4*)&acc[12];
    }
}

// ---------------- BatchNorm ----------------

__global__ void bn_stats(const float* __restrict__ x, int n,
                         float* __restrict__ sums, float* __restrict__ sumsq) {
    int c = threadIdx.x;   // 128
    float s = 0.f, s2 = 0.f;
    for (int r = blockIdx.x; r < n; r += gridDim.x) {
        float v = x[(size_t)r * 128 + c];
        s += v; s2 += v * v;
    }
    atomicAdd(&sums[c], s);
    atomicAdd(&sumsq[c], s2);
}

// BN finalize (per-thread from sums/sumsq) + affine + ReLU + 4-bit fake-quant -> u8
__global__ void bn_apply_quant_u8(const float* __restrict__ x,
                                  const float* __restrict__ sums,
                                  const float* __restrict__ sumsq,
                                  const float* __restrict__ g, const float* __restrict__ b,
                                  const float* __restrict__ gs,
                                  unsigned char* __restrict__ out, int n) {
    int idx = blockIdx.x * blockDim.x + threadIdx.x;
    if (idx >= n * 128) return;
    int c = idx & 127;
    int r = idx >> 7;
    float m  = sums[c] / (float)n;
    float vr = sumsq[c] / (float)n - m * m;
    float a  = g[c] * (1.0f / sqrtf(vr + 1e-5f));
    float bp = b[c] - m * a;
    float v = a * x[idx] + bp;
    v = fmaxf(v, 0.0f);
    float qv = fminf(fmaxf(v / gs[r], 0.0f), 15.0f);
    out[idx] = (unsigned char)rintf(qv);   // round-half-even
}

// ---------------- log_softmax (one wave per row) ----------------

__global__ void log_softmax_rows(const float* __restrict__ z, float* __restrict__ out,
                                 int n, int C) {
    int rowsPerBlock = blockDim.x / 64;
    int row = blockIdx.x * rowsPerBlock + (threadIdx.x / 64);
    int lane = threadIdx.x & 63;
    if (row >= n) return;
    float v = (lane < C) ? z[(size_t)row * C + lane] : -INFINITY;
    float m = v;
#pragma unroll
    for (int o = 32; o; o >>= 1) m = fmaxf(m, __shfl_xor(m, o));
    float e = (lane < C) ? expf(v - m) : 0.0f;
    float s = e;
#pragma unroll
    for (int o = 32; o; o >>= 1) s += __shfl_xor(s, o);
    if (lane < C) out[(size_t)row * C + lane] = v - m - logf(s);
}

// ---------------- launch ----------------

extern "C" void kernel_launch(void* const* d_in, const int* in_sizes, int n_in,
                              void* d_out, int out_size, void* d_ws, size_t ws_size,
                              hipStream_t stream) {
    float*       xbuf = (float*)d_in[0];          // reused as scratch after layer-1 GEMM
    const int*   ei   = (const int*)d_in[1];
    const float* W1   = (const float*)d_in[2];
    const float* b1   = (const float*)d_in[3];
    const float* a1   = (const float*)d_in[4];
    const float* W2   = (const float*)d_in[5];
    const float* b2   = (const float*)d_in[6];
    const float* a2   = (const float*)d_in[7];
    const float* g2   = (const float*)d_in[8];
    const float* W3   = (const float*)d_in[9];
    const float* b3   = (const float*)d_in[10];
    const float* a3   = (const float*)d_in[11];
    const float* g3   = (const float*)d_in[12];
    const float* bn1g = (const float*)d_in[13];
    const float* bn1b = (const float*)d_in[14];
    const float* bn2g = (const float*)d_in[15];
    const float* bn2b = (const float*)d_in[16];

    const int n = in_sizes[0] / 128;      // 50000
    const int E = in_sizes[1] / 2;        // 800000
    const int C = in_sizes[9] / 128;      // 40
    const int* src = ei;
    const int* dst = ei + E;

    // ---- workspace layout: zeroed region FIRST (one memset covers it) ----
    char* wsp = (char*)d_ws;
    size_t off = 0;
    auto take = [&](size_t bytes) -> void* {
        void* p = wsp + off;
        off += (bytes + 255) & ~(size_t)255;
        return p;
    };
    int*   indeg   = (int*)take((size_t)n * 4);
    int*   counter = (int*)take(4);
    float* stats1  = (float*)take(256 * 4);       // sums1 | sumsq1
    float* stats2  = (float*)take(256 * 4);       // sums2 | sumsq2
    size_t zeroBytes = off;                        // memset range end
    int*   startA  = (int*)take((size_t)n * 4);
    int*   cursor  = (int*)take((size_t)n * 4);
    float* dinv    = (float*)take((size_t)n * 4);
    float* rowsum  = (float*)take((size_t)n * 4);
    int*   ssrc    = (int*)take((size_t)E * 4);
    float* w1q     = (float*)take(128 * 128 * 4);
    float* w2q     = (float*)take(128 * 128 * 4);
    float* w3q     = (float*)take((size_t)128 * C * 4);
    unsigned char* qbuf = (unsigned char*)take((size_t)n * 128);
    float* hbuf    = (float*)take((size_t)n * 128 * 4);

    float* outF  = (float*)d_out;

    // ---- setup: 1 memset + 4 kernels ----
    hipMemsetAsync(d_ws, 0, zeroBytes, stream);
    count_indeg<<<(E + 255) / 256, 256, 0, stream>>>(dst, E, indeg);
    dinv_ranges<<<(n + 255) / 256, 256, 0, stream>>>(indeg, dinv, startA, cursor, counter, n);
    fill_csr<<<(E + 255) / 256, 256, 0, stream>>>(src, dst, E, cursor, ssrc);
    const int nW = 128 * 128 + 128 * 128 + 128 * C;
    quant_w_all<<<(nW + 255) / 256, 256, 0, stream>>>(W1, a1, W2, a2, W3, a3,
                                                      w1q, w2q, w3q,
                                                      128 * 128, 128 * 128, 128 * C);

    const int gElem128 = (n * 128 + 255) / 256;
    const int gWave = (n + 3) / 4;
    dim3 grid128((n + TM - 1) / TM, (128 + TN - 1) / TN);
    dim3 gridC((n + TM - 1) / TM, (C + TN - 1) / TN);

    // ---- layer 1 ----
    gemm_bias_tiled<<<grid128, 256, 0, stream>>>(xbuf, w1q, b1, nullptr, hbuf, n, 128, 128);
    aggregate128_par<<<n, 256, 0, stream>>>(hbuf, dinv, startA, indeg, ssrc, xbuf, n, E);
    bn_stats<<<512, 128, 0, stream>>>(xbuf, n, stats1, stats1 + 128);
    bn_apply_quant_u8<<<gElem128, 256, 0, stream>>>(xbuf, stats1, stats1 + 128,
                                                    bn1g, bn1b, g2, qbuf, n);

    // ---- layer 2: aggregate(q)*W + rowsum*b (linearity swap) ----
    aggregate_q8_wave<<<gWave, 256, 0, stream>>>(qbuf, dinv, g2, startA, indeg, ssrc,
                                                 hbuf, rowsum, n, E);
    gemm_bias_tiled<<<grid128, 256, 0, stream>>>(hbuf, w2q, b2, rowsum, xbuf, n, 128, 128);
    bn_stats<<<512, 128, 0, stream>>>(xbuf, n, stats2, stats2 + 128);
    bn_apply_quant_u8<<<gElem128, 256, 0, stream>>>(xbuf, stats2, stats2 + 128,
                                                    bn2g, bn2b, g3, qbuf, n);

    // ---- layer 3: aggregate(q)*W3 + rowsum*b3, then log_softmax ----
    aggregate_q8_wave<<<gWave, 256, 0, stream>>>(qbuf, dinv, g3, startA, indeg, ssrc,
                                                 hbuf, rowsum, n, E);
    gemm_bias_tiled<<<gridC, 256, 0, stream>>>(hbuf, w3q, b3, rowsum, xbuf, n, C, 128);
    log_softmax_rows<<<(n + 3) / 4, 256, 0, stream>>>(xbuf, outF, n, C);
}

// Round 9
// 516.318 us; speedup vs baseline: 1.1767x; 1.0277x over previous
//
#include <hip/hip_runtime.h>
#include <hip/hip_bf16.h>
#include <math.h>

// ---------------- graph structure ----------------

__global__ void count_indeg(const int* __restrict__ dst, int e, int* __restrict__ indeg) {
    int i = blockIdx.x * blockDim.x + threadIdx.x;
    if (i < e) atomicAdd(&indeg[dst[i]], 1);
}

// fused setup: dinv + disjoint ranges (i < n)  |  weight fake-quant (i < nW)
__global__ void setup_misc(const int* __restrict__ indeg, float* __restrict__ dinv,
                           int* __restrict__ start, int* __restrict__ cursor,
                           int* __restrict__ counter, int n,
                           const float* __restrict__ W1, const float* __restrict__ a1,
                           const float* __restrict__ W2, const float* __restrict__ a2,
                           const float* __restrict__ W3, const float* __restrict__ a3,
                           float* __restrict__ w1q, float* __restrict__ w2q,
                           float* __restrict__ w3q, int n1, int n2, int n3) {
    int i = blockIdx.x * blockDim.x + threadIdx.x;
    if (i < n) {
        int d = indeg[i];
        dinv[i] = 1.0f / sqrtf((float)(d + 1));
        int s = atomicAdd(counter, d);
        start[i] = s;
        cursor[i] = s;
    }
    const float* w; const float* a; float* o; int k;
    if (i < n1) { w = W1; a = a1; o = w1q; k = i; }
    else if (i < n1 + n2) { w = W2; a = a2; o = w2q; k = i - n1; }
    else if (i < n1 + n2 + n3) { w = W3; a = a3; o = w3q; k = i - n1 - n2; }
    else return;
    float s = a[0];
    float v = w[k] / s;
    v = fminf(fmaxf(v, -8.0f), 7.0f);
    o[k] = rintf(v) * s;   // round-half-even, matches jnp.round
}

// CSR fill + per-edge src-side weights: w=dinv[s], gw2=dinv[s]*g2[s], gw3=dinv[s]*g3[s]
__global__ void fill_csr_w(const int* __restrict__ src, const int* __restrict__ dst, int e,
                           int* __restrict__ cursor, const float* __restrict__ dinv,
                           const float* __restrict__ g2, const float* __restrict__ g3,
                           int* __restrict__ ssrc, float* __restrict__ wsrc,
                           float* __restrict__ gw2, float* __restrict__ gw3, int n) {
    int i = blockIdx.x * blockDim.x + threadIdx.x;
    if (i < e) {
        int s = src[i];
        int p = atomicAdd(&cursor[dst[i]], 1);
        if (p >= 0 && p < e && (unsigned)s < (unsigned)n) {
            float ds = dinv[s];
            ssrc[p] = s;
            wsrc[p] = ds;
            gw2[p] = ds * g2[s];
            gw3[p] = ds * g3[s];
        }
    }
}

// rowsum[i] = di*di + di * sum_e dinv[src_e]   (bias propagation; layer-independent)
__global__ void rowsum_k(const float* __restrict__ wsrc, const float* __restrict__ dinv,
                         const int* __restrict__ start, const int* __restrict__ indeg,
                         float* __restrict__ rowsum, int n, int E) {
    int i = blockIdx.x * blockDim.x + threadIdx.x;
    if (i >= n) return;
    float di = dinv[i];
    int s0 = start[i];
    int len = indeg[i];
    if (s0 < 0) s0 = 0;
    if (len < 0) len = 0;
    if (s0 + len > E) len = (E - s0 > 0) ? (E - s0) : 0;
    float s = 0.f;
    for (int j = 0; j < len; ++j) s += wsrc[s0 + j];
    rowsum[i] = di * di + di * s;
}

// ---------------- GEMM 128-col: C[M,128] = A[M,128] @ B[128,128] + rs*bias ----------------
// 128x128 tile, 256 threads, 8x8 microtile (two 4-col blocks -> all LDS reads <=2-way).

__global__ __launch_bounds__(256) void gemm128_bias(
        const float* __restrict__ A, const float* __restrict__ B,
        const float* __restrict__ bias, const float* __restrict__ rowsum,
        float* __restrict__ C, int M, int K) {
    __shared__ float sA[16][132];
    __shared__ float sB[16][132];
    int tid = threadIdx.x;
    int rowBase = blockIdx.x * 128;
    int tx = tid & 15;       // col groups at tx*4 and 64+tx*4
    int ty = tid >> 4;       // rows ty*8..ty*8+7
    float acc[8][8] = {};

    int aRow = tid >> 1;
    int aK   = (tid & 1) * 8;
    int bK   = tid >> 4;          // 0..15
    int bCol = (tid & 15) * 8;    // 0..120

    for (int k0 = 0; k0 < K; k0 += 16) {
        int gRow = rowBase + aRow;
        if (gRow >= M) gRow = M - 1;            // clamp; discarded at store
        const float* ap = A + (size_t)gRow * K + k0 + aK;
        float4 a0 = *(const float4*)ap;
        float4 a1 = *(const float4*)(ap + 4);
        sA[aK + 0][aRow] = a0.x;
        sA[aK + 1][aRow] = a0.y;
        sA[aK + 2][aRow] = a0.z;
        sA[aK + 3][aRow] = a0.w;
        sA[aK + 4][aRow] = a1.x;
        sA[aK + 5][aRow] = a1.y;
        sA[aK + 6][aRow] = a1.z;
        sA[aK + 7][aRow] = a1.w;
        const float* bp = B + (size_t)(k0 + bK) * 128 + bCol;
        *(float4*)&sB[bK][bCol]     = *(const float4*)bp;
        *(float4*)&sB[bK][bCol + 4] = *(const float4*)(bp + 4);
        __syncthreads();

#pragma unroll
        for (int kk = 0; kk < 16; ++kk) {
            float4 av0 = *(const float4*)&sA[kk][ty * 8];
            float4 av1 = *(const float4*)&sA[kk][ty * 8 + 4];
            float4 bv0 = *(const float4*)&sB[kk][tx * 4];
            float4 bv1 = *(const float4*)&sB[kk][64 + tx * 4];
            float a[8] = {av0.x, av0.y, av0.z, av0.w, av1.x, av1.y, av1.z, av1.w};
            float b[8] = {bv0.x, bv0.y, bv0.z, bv0.w, bv1.x, bv1.y, bv1.z, bv1.w};
#pragma unroll
            for (int i = 0; i < 8; ++i)
#pragma unroll
                for (int j = 0; j < 8; ++j)
                    acc[i][j] = fmaf(a[i], b[j], acc[i][j]);
        }
        __syncthreads();
    }

    int c0 = tx * 4, c1 = 64 + tx * 4;
    float bb[8];
#pragma unroll
    for (int j = 0; j < 4; ++j) { bb[j] = bias[c0 + j]; bb[4 + j] = bias[c1 + j]; }
#pragma unroll
    for (int i = 0; i < 8; ++i) {
        int row = rowBase + ty * 8 + i;
        if (row >= M) continue;
        float rs = rowsum ? rowsum[row] : 1.0f;
        float4 v0 = {acc[i][0] + rs * bb[0], acc[i][1] + rs * bb[1],
                     acc[i][2] + rs * bb[2], acc[i][3] + rs * bb[3]};
        float4 v1 = {acc[i][4] + rs * bb[4], acc[i][5] + rs * bb[5],
                     acc[i][6] + rs * bb[6], acc[i][7] + rs * bb[7]};
        *(float4*)&C[(size_t)row * 128 + c0] = v0;
        *(float4*)&C[(size_t)row * 128 + c1] = v1;
    }
}

// ---------------- layer-3 GEMM (N<=64) + fused log_softmax ----------------

__global__ __launch_bounds__(256) void gemm40_softmax(
        const float* __restrict__ A, const float* __restrict__ B,
        const float* __restrict__ bias, const float* __restrict__ rowsum,
        float* __restrict__ out, int M, int N, int K) {
    __shared__ float sA[16][132];
    __shared__ float sB[16][68];
    __shared__ float sOut[128][41];
    int tid = threadIdx.x;
    int rowBase = blockIdx.x * 128;
    int tx = tid & 15;
    int ty = tid >> 4;
    float acc[8][4] = {};

    int aRow = tid >> 1;
    int aK   = (tid & 1) * 8;
    int bK   = tid >> 4;
    int bCol = (tid & 15) * 4;

    for (int k0 = 0; k0 < K; k0 += 16) {
        int gRow = rowBase + aRow;
        if (gRow >= M) gRow = M - 1;
        const float* ap = A + (size_t)gRow * K + k0 + aK;
        float4 a0 = *(const float4*)ap;
        float4 a1 = *(const float4*)(ap + 4);
        sA[aK + 0][aRow] = a0.x;
        sA[aK + 1][aRow] = a0.y;
        sA[aK + 2][aRow] = a0.z;
        sA[aK + 3][aRow] = a0.w;
        sA[aK + 4][aRow] = a1.x;
        sA[aK + 5][aRow] = a1.y;
        sA[aK + 6][aRow] = a1.z;
        sA[aK + 7][aRow] = a1.w;
#pragma unroll
        for (int j = 0; j < 4; ++j) {
            int col = bCol + j;
            sB[bK][col] = (col < N) ? B[(size_t)(k0 + bK) * N + col] : 0.0f;
        }
        __syncthreads();
#pragma unroll
        for (int kk = 0; kk < 16; ++kk) {
            float4 av0 = *(const float4*)&sA[kk][ty * 8];
            float4 av1 = *(const float4*)&sA[kk][ty * 8 + 4];
            float4 bv  = *(const float4*)&sB[kk][tx * 4];
            float a[8] = {av0.x, av0.y, av0.z, av0.w, av1.x, av1.y, av1.z, av1.w};
            float b[4] = {bv.x, bv.y, bv.z, bv.w};
#pragma unroll
            for (int i = 0; i < 8; ++i)
#pragma unroll
                for (int j = 0; j < 4; ++j)
                    acc[i][j] = fmaf(a[i], b[j], acc[i][j]);
        }
        __syncthreads();
    }

    int colOut = tx * 4;
    float bb[4];
#pragma unroll
    for (int j = 0; j < 4; ++j) bb[j] = (colOut + j < N) ? bias[colOut + j] : 0.0f;
#pragma unroll
    for (int i = 0; i < 8; ++i) {
        int rowL = ty * 8 + i;
        int row = rowBase + rowL;
        float rs = (row < M && rowsum) ? rowsum[row] : 1.0f;
#pragma unroll
        for (int j = 0; j < 4; ++j)
            if (colOut + j < N) sOut[rowL][colOut + j] = acc[i][j] + rs * bb[j];
    }
    __syncthreads();
    // log_softmax per row (threads 0..127, one row each)
    if (tid < 128) {
        int row = rowBase + tid;
        if (row < M) {
            float mx = -INFINITY;
            for (int c = 0; c < N; ++c) mx = fmaxf(mx, sOut[tid][c]);
            float sm = 0.f;
            for (int c = 0; c < N; ++c) sm += expf(sOut[tid][c] - mx);
            float lg = mx + logf(sm);
            float* op = out + (size_t)row * N;
            for (int c = 0; c < N; ++c) op[c] = sOut[tid][c] - lg;
        }
    }
}

// ---------------- fp32 aggregation (layer 1): block per node, LDS-staged ----------------
// staging is now fully coalesced (ssrc + wsrc arrays); weight = wsrc*di.

__global__ __launch_bounds__(256) void aggregate128_par(
        const float* __restrict__ h, const float* __restrict__ dinv,
        const float* __restrict__ wsrc,
        const int* __restrict__ start, const int* __restrict__ indeg,
        const int* __restrict__ ssrc, float* __restrict__ out, int n, int E) {
    __shared__ int   sIdx[256];
    __shared__ float sW[256];
    __shared__ float red[8][132];
    int node = blockIdx.x;
    int tid = threadIdx.x;
    int c4 = (tid & 31) * 4;
    int slot = tid >> 5;
    float di = dinv[node];
    int s0 = start[node];
    int len = indeg[node];
    if (s0 < 0) s0 = 0;
    if (len < 0) len = 0;
    if (s0 + len > E) len = (E - s0 > 0) ? (E - s0) : 0;

    float4 acc = {0.f, 0.f, 0.f, 0.f};
    for (int chunk = 0; chunk < len; chunk += 256) {
        int m = len - chunk; if (m > 256) m = 256;
        if (tid < m) {
            int s = ssrc[s0 + chunk + tid];
            float w = wsrc[s0 + chunk + tid] * di;
            if ((unsigned)s >= (unsigned)n) { s = node; w = 0.f; }
            sIdx[tid] = s; sW[tid] = w;
        }
        __syncthreads();
        int j = slot;
        for (; j + 8 < m; j += 16) {
            int sa = sIdx[j], sb = sIdx[j + 8];
            float wa = sW[j], wb = sW[j + 8];
            float4 va = *(const float4*)(h + (size_t)sa * 128 + c4);
            float4 vb = *(const float4*)(h + (size_t)sb * 128 + c4);
            acc.x = fmaf(va.x, wa, acc.x); acc.y = fmaf(va.y, wa, acc.y);
            acc.z = fmaf(va.z, wa, acc.z); acc.w = fmaf(va.w, wa, acc.w);
            acc.x = fmaf(vb.x, wb, acc.x); acc.y = fmaf(vb.y, wb, acc.y);
            acc.z = fmaf(vb.z, wb, acc.z); acc.w = fmaf(vb.w, wb, acc.w);
        }
        if (j < m) {
            int sa = sIdx[j];
            float wa = sW[j];
            float4 va = *(const float4*)(h + (size_t)sa * 128 + c4);
            acc.x = fmaf(va.x, wa, acc.x); acc.y = fmaf(va.y, wa, acc.y);
            acc.z = fmaf(va.z, wa, acc.z); acc.w = fmaf(va.w, wa, acc.w);
        }
        __syncthreads();
    }
    *(float4*)&red[slot][c4] = acc;
    __syncthreads();
    if (tid < 128) {
        int c = tid;
        float r = h[(size_t)node * 128 + c] * di * di;    // self loop
#pragma unroll
        for (int s = 0; s < 8; ++s) r += red[s][c];
        out[(size_t)node * 128 + c] = r;
    }
}

// ---------------- u8 aggregation (layers 2,3): one WAVE per node ----------------
// Weight gw[] precomputed -> serial chain is ssrc -> row gather only.

__device__ __forceinline__ void unpack_fma(float* acc, uint4 v, float w) {
    acc[0]  = fmaf((float)(v.x & 255), w, acc[0]);
    acc[1]  = fmaf((float)((v.x >> 8) & 255), w, acc[1]);
    acc[2]  = fmaf((float)((v.x >> 16) & 255), w, acc[2]);
    acc[3]  = fmaf((float)(v.x >> 24), w, acc[3]);
    acc[4]  = fmaf((float)(v.y & 255), w, acc[4]);
    acc[5]  = fmaf((float)((v.y >> 8) & 255), w, acc[5]);
    acc[6]  = fmaf((float)((v.y >> 16) & 255), w, acc[6]);
    acc[7]  = fmaf((float)(v.y >> 24), w, acc[7]);
    acc[8]  = fmaf((float)(v.z & 255), w, acc[8]);
    acc[9]  = fmaf((float)((v.z >> 8) & 255), w, acc[9]);
    acc[10] = fmaf((float)((v.z >> 16) & 255), w, acc[10]);
    acc[11] = fmaf((float)(v.z >> 24), w, acc[11]);
    acc[12] = fmaf((float)(v.w & 255), w, acc[12]);
    acc[13] = fmaf((float)((v.w >> 8) & 255), w, acc[13]);
    acc[14] = fmaf((float)((v.w >> 16) & 255), w, acc[14]);
    acc[15] = fmaf((float)(v.w >> 24), w, acc[15]);
}

__global__ __launch_bounds__(256) void aggregate_q8_wave(
        const unsigned char* __restrict__ q, const float* __restrict__ dinv,
        const float* __restrict__ gscale, const float* __restrict__ gw,
        const int* __restrict__ start, const int* __restrict__ indeg,
        const int* __restrict__ ssrc, float* __restrict__ out, int n, int E) {
    int node = blockIdx.x * 4 + (threadIdx.x >> 6);
    if (node >= n) return;
    int lane = threadIdx.x & 63;
    int slot = lane >> 3;      // 0..7
    int sl   = lane & 7;       // covers bytes sl*16..sl*16+15
    float di = dinv[node];
    int s0 = start[node];
    int len = indeg[node];
    if (s0 < 0) s0 = 0;
    if (len < 0) len = 0;
    if (s0 + len > E) len = (E - s0 > 0) ? (E - s0) : 0;

    float acc[16] = {};
    int j = slot;
    for (; j + 8 < len; j += 16) {
        int sa = ssrc[s0 + j];
        int sb = ssrc[s0 + j + 8];
        float wa = gw[s0 + j] * di;
        float wb = gw[s0 + j + 8] * di;
        if ((unsigned)sa >= (unsigned)n) { sa = node; wa = 0.f; }
        if ((unsigned)sb >= (unsigned)n) { sb = node; wb = 0.f; }
        uint4 va = *(const uint4*)(q + (size_t)sa * 128 + sl * 16);
        uint4 vb = *(const uint4*)(q + (size_t)sb * 128 + sl * 16);
        unpack_fma(acc, va, wa);
        unpack_fma(acc, vb, wb);
    }
    if (j < len) {
        int sa = ssrc[s0 + j];
        float wa = gw[s0 + j] * di;
        if ((unsigned)sa >= (unsigned)n) { sa = node; wa = 0.f; }
        uint4 va = *(const uint4*)(q + (size_t)sa * 128 + sl * 16);
        unpack_fma(acc, va, wa);
    }
#pragma unroll
    for (int o = 8; o < 64; o <<= 1) {
#pragma unroll
        for (int k = 0; k < 16; ++k) acc[k] += __shfl_xor(acc[k], o);
    }
    if (slot == 0) {
        uint4 vs = *(const uint4*)(q + (size_t)node * 128 + sl * 16);
        unpack_fma(acc, vs, gscale[node] * di * di);   // self loop
        float* op = out + (size_t)node * 128 + sl * 16;
        *(float4*)(op + 0)  = *(float4*)&acc[0];
        *(float4*)(op + 4)  = *(float4*)&acc[4];
        *(float4*)(op + 8)  = *(float4*)&acc[8];
        *(float4*)(op + 12) = *(float4*)&acc[12];
    }
}

// ---------------- BatchNorm ----------------

__global__ void bn_stats(const float* __restrict__ x, int n,
                         float* __restrict__ sums, float* __restrict__ sumsq) {
    int c = threadIdx.x;   // 128
    float s = 0.f, s2 = 0.f;
    for (int r = blockIdx.x; r < n; r += gridDim.x) {
        float v = x[(size_t)r * 128 + c];
        s += v; s2 += v * v;
    }
    atomicAdd(&sums[c], s);
    atomicAdd(&sumsq[c], s2);
}

// BN finalize (per-thread) + affine + ReLU + 4-bit fake-quant -> u8
__global__ void bn_apply_quant_u8(const float* __restrict__ x,
                                  const float* __restrict__ sums,
                                  const float* __restrict__ sumsq,
                                  const float* __restrict__ g, const float* __restrict__ b,
                                  const float* __restrict__ gs,
                                  unsigned char* __restrict__ out, int n) {
    int idx = blockIdx.x * blockDim.x + threadIdx.x;
    if (idx >= n * 128) return;
    int c = idx & 127;
    int r = idx >> 7;
    float m  = sums[c] / (float)n;
    float vr = sumsq[c] / (float)n - m * m;
    float a  = g[c] * (1.0f / sqrtf(vr + 1e-5f));
    float bp = b[c] - m * a;
    float v = a * x[idx] + bp;
    v = fmaxf(v, 0.0f);
    float qv = fminf(fmaxf(v / gs[r], 0.0f), 15.0f);
    out[idx] = (unsigned char)rintf(qv);   // round-half-even
}

// ---------------- launch ----------------

extern "C" void kernel_launch(void* const* d_in, const int* in_sizes, int n_in,
                              void* d_out, int out_size, void* d_ws, size_t ws_size,
                              hipStream_t stream) {
    float*       xbuf = (float*)d_in[0];          // reused as scratch after layer-1 GEMM
    const int*   ei   = (const int*)d_in[1];
    const float* W1   = (const float*)d_in[2];
    const float* b1   = (const float*)d_in[3];
    const float* a1   = (const float*)d_in[4];
    const float* W2   = (const float*)d_in[5];
    const float* b2   = (const float*)d_in[6];
    const float* a2   = (const float*)d_in[7];
    const float* g2   = (const float*)d_in[8];
    const float* W3   = (const float*)d_in[9];
    const float* b3   = (const float*)d_in[10];
    const float* a3   = (const float*)d_in[11];
    const float* g3   = (const float*)d_in[12];
    const float* bn1g = (const float*)d_in[13];
    const float* bn1b = (const float*)d_in[14];
    const float* bn2g = (const float*)d_in[15];
    const float* bn2b = (const float*)d_in[16];

    const int n = in_sizes[0] / 128;      // 50000
    const int E = in_sizes[1] / 2;        // 800000
    const int C = in_sizes[9] / 128;      // 40
    const int* src = ei;
    const int* dst = ei + E;

    // ---- workspace layout: zeroed region FIRST ----
    char* wsp = (char*)d_ws;
    size_t off = 0;
    auto take = [&](size_t bytes) -> void* {
        void* p = wsp + off;
        off += (bytes + 255) & ~(size_t)255;
        return p;
    };
    int*   indeg   = (int*)take((size_t)n * 4);
    int*   counter = (int*)take(4);
    float* stats1  = (float*)take(256 * 4);       // sums1 | sumsq1
    float* stats2  = (float*)take(256 * 4);       // sums2 | sumsq2
    size_t zeroBytes = off;
    int*   startA  = (int*)take((size_t)n * 4);
    int*   cursor  = (int*)take((size_t)n * 4);
    float* dinv    = (float*)take((size_t)n * 4);
    float* rowsum  = (float*)take((size_t)n * 4);
    int*   ssrc    = (int*)take((size_t)E * 4);
    float* wsrc    = (float*)take((size_t)E * 4);
    float* gw2     = (float*)take((size_t)E * 4);
    float* gw3     = (float*)take((size_t)E * 4);
    float* w1q     = (float*)take(128 * 128 * 4);
    float* w2q     = (float*)take(128 * 128 * 4);
    float* w3q     = (float*)take((size_t)128 * C * 4);
    unsigned char* qbuf = (unsigned char*)take((size_t)n * 128);
    float* hbuf    = (float*)take((size_t)n * 128 * 4);

    float* outF  = (float*)d_out;

    // ---- setup ----
    hipMemsetAsync(d_ws, 0, zeroBytes, stream);
    count_indeg<<<(E + 255) / 256, 256, 0, stream>>>(dst, E, indeg);
    const int nW = 128 * 128 + 128 * 128 + 128 * C;
    int setupN = (n > nW) ? n : nW;
    setup_misc<<<(setupN + 255) / 256, 256, 0, stream>>>(
        indeg, dinv, startA, cursor, counter, n,
        W1, a1, W2, a2, W3, a3, w1q, w2q, w3q, 128 * 128, 128 * 128, 128 * C);
    fill_csr_w<<<(E + 255) / 256, 256, 0, stream>>>(src, dst, E, cursor, dinv, g2, g3,
                                                    ssrc, wsrc, gw2, gw3, n);
    rowsum_k<<<(n + 255) / 256, 256, 0, stream>>>(wsrc, dinv, startA, indeg, rowsum, n, E);

    const int gElem128 = (n * 128 + 255) / 256;
    const int gWave = (n + 3) / 4;
    const int gRow128 = (n + 127) / 128;

    // ---- layer 1 ----
    gemm128_bias<<<gRow128, 256, 0, stream>>>(xbuf, w1q, b1, nullptr, hbuf, n, 128);
    aggregate128_par<<<n, 256, 0, stream>>>(hbuf, dinv, wsrc, startA, indeg, ssrc, xbuf, n, E);
    bn_stats<<<512, 128, 0, stream>>>(xbuf, n, stats1, stats1 + 128);
    bn_apply_quant_u8<<<gElem128, 256, 0, stream>>>(xbuf, stats1, stats1 + 128,
                                                    bn1g, bn1b, g2, qbuf, n);

    // ---- layer 2: aggregate(q)*W + rowsum*b ----
    aggregate_q8_wave<<<gWave, 256, 0, stream>>>(qbuf, dinv, g2, gw2, startA, indeg,
                                                 ssrc, hbuf, n, E);
    gemm128_bias<<<gRow128, 256, 0, stream>>>(hbuf, w2q, b2, rowsum, xbuf, n, 128);
    bn_stats<<<512, 128, 0, stream>>>(xbuf, n, stats2, stats2 + 128);
    bn_apply_quant_u8<<<gElem128, 256, 0, stream>>>(xbuf, stats2, stats2 + 128,
                                                    bn2g, bn2b, g3, qbuf, n);

    // ---- layer 3: aggregate(q)*W3 + rowsum*b3, softmax fused ----
    aggregate_q8_wave<<<gWave, 256, 0, stream>>>(qbuf, dinv, g3, gw3, startA, indeg,
                                                 ssrc, hbuf, n, E);
    gemm40_softmax<<<gRow128, 256, 0, stream>>>(hbuf, w3q, b3, rowsum, outF, n, C, 128);
}

// Round 10
// 479.686 us; speedup vs baseline: 1.2666x; 1.0764x over previous
//
#include <hip/hip_runtime.h>
#include <hip/hip_bf16.h>
#include <math.h>

// ---------------- graph structure ----------------

__global__ void count_indeg(const int* __restrict__ dst, int e, int* __restrict__ indeg) {
    int i = blockIdx.x * blockDim.x + threadIdx.x;
    if (i < e) atomicAdd(&indeg[dst[i]], 1);
}

// fused setup: dinv + disjoint ranges (i < n)  |  weight fake-quant (i < nW)
__global__ void setup_misc(const int* __restrict__ indeg, float* __restrict__ dinv,
                           int* __restrict__ start, int* __restrict__ cursor,
                           int* __restrict__ counter, int n,
                           const float* __restrict__ W1, const float* __restrict__ a1,
                           const float* __restrict__ W2, const float* __restrict__ a2,
                           const float* __restrict__ W3, const float* __restrict__ a3,
                           float* __restrict__ w1q, float* __restrict__ w2q,
                           float* __restrict__ w3q, int n1, int n2, int n3) {
    int i = blockIdx.x * blockDim.x + threadIdx.x;
    if (i < n) {
        int d = indeg[i];
        dinv[i] = 1.0f / sqrtf((float)(d + 1));
        int s = atomicAdd(counter, d);
        start[i] = s;
        cursor[i] = s;
    }
    const float* w; const float* a; float* o; int k;
    if (i < n1) { w = W1; a = a1; o = w1q; k = i; }
    else if (i < n1 + n2) { w = W2; a = a2; o = w2q; k = i - n1; }
    else if (i < n1 + n2 + n3) { w = W3; a = a3; o = w3q; k = i - n1 - n2; }
    else return;
    float s = a[0];
    float v = w[k] / s;
    v = fminf(fmaxf(v, -8.0f), 7.0f);
    o[k] = rintf(v) * s;   // round-half-even, matches jnp.round
}

// CSR fill, packed edge record {src, dinv_s, dinv_s*g2, dinv_s*g3} (one 16B store),
// plus colsum[dst] += dinv[src] for bias-propagation rowsum.
__global__ void fill_csr_packed(const int* __restrict__ src, const int* __restrict__ dst,
                                int e, int* __restrict__ cursor,
                                const float* __restrict__ dinv,
                                const float* __restrict__ g2, const float* __restrict__ g3,
                                int4* __restrict__ epack, float* __restrict__ colsum, int n) {
    int i = blockIdx.x * blockDim.x + threadIdx.x;
    if (i >= e) return;
    int s = src[i];
    int d = dst[i];
    int p = atomicAdd(&cursor[d], 1);
    if (p < 0 || p >= e) return;
    int4 rec;
    if ((unsigned)s < (unsigned)n) {
        float ds = dinv[s];
        rec.x = s;
        rec.y = __float_as_int(ds);
        rec.z = __float_as_int(ds * g2[s]);
        rec.w = __float_as_int(ds * g3[s]);
        atomicAdd(&colsum[d], ds);
    } else {
        rec.x = -1; rec.y = 0; rec.z = 0; rec.w = 0;
    }
    epack[p] = rec;
}

// ---------------- GEMM 128-col + optional fused BN-stats partials ----------------
// C[M,128] = A[M,128] @ B[128,128] + rs*bias,  rs = di^2 + di*colsum (or 1).
// statsP (64 copies x 256): sums|sumsq accumulated via atomics if non-null.

__global__ __launch_bounds__(256) void gemm128_bias(
        const float* __restrict__ A, const float* __restrict__ B,
        const float* __restrict__ bias,
        const float* __restrict__ dinv, const float* __restrict__ colsum,
        float* __restrict__ C, float* __restrict__ statsP, int M, int K) {
    __shared__ float sA[16][132];
    __shared__ float sB[16][132];
    int tid = threadIdx.x;
    int rowBase = blockIdx.x * 128;
    int tx = tid & 15;       // col groups at tx*4 and 64+tx*4
    int ty = tid >> 4;       // rows ty*8..ty*8+7
    float acc[8][8] = {};

    int aRow = tid >> 1;
    int aK   = (tid & 1) * 8;
    int bK   = tid >> 4;          // 0..15
    int bCol = (tid & 15) * 8;    // 0..120

    for (int k0 = 0; k0 < K; k0 += 16) {
        int gRow = rowBase + aRow;
        if (gRow >= M) gRow = M - 1;            // clamp; discarded at store
        const float* ap = A + (size_t)gRow * K + k0 + aK;
        float4 a0 = *(const float4*)ap;
        float4 a1 = *(const float4*)(ap + 4);
        sA[aK + 0][aRow] = a0.x;
        sA[aK + 1][aRow] = a0.y;
        sA[aK + 2][aRow] = a0.z;
        sA[aK + 3][aRow] = a0.w;
        sA[aK + 4][aRow] = a1.x;
        sA[aK + 5][aRow] = a1.y;
        sA[aK + 6][aRow] = a1.z;
        sA[aK + 7][aRow] = a1.w;
        const float* bp = B + (size_t)(k0 + bK) * 128 + bCol;
        *(float4*)&sB[bK][bCol]     = *(const float4*)bp;
        *(float4*)&sB[bK][bCol + 4] = *(const float4*)(bp + 4);
        __syncthreads();

#pragma unroll
        for (int kk = 0; kk < 16; ++kk) {
            float4 av0 = *(const float4*)&sA[kk][ty * 8];
            float4 av1 = *(const float4*)&sA[kk][ty * 8 + 4];
            float4 bv0 = *(const float4*)&sB[kk][tx * 4];
            float4 bv1 = *(const float4*)&sB[kk][64 + tx * 4];
            float a[8] = {av0.x, av0.y, av0.z, av0.w, av1.x, av1.y, av1.z, av1.w};
            float b[8] = {bv0.x, bv0.y, bv0.z, bv0.w, bv1.x, bv1.y, bv1.z, bv1.w};
#pragma unroll
            for (int i = 0; i < 8; ++i)
#pragma unroll
                for (int j = 0; j < 8; ++j)
                    acc[i][j] = fmaf(a[i], b[j], acc[i][j]);
        }
        __syncthreads();
    }

    int c0 = tx * 4, c1 = 64 + tx * 4;
    float bb[8];
#pragma unroll
    for (int j = 0; j < 4; ++j) { bb[j] = bias[c0 + j]; bb[4 + j] = bias[c1 + j]; }
    float s1[8] = {}, s2[8] = {};
#pragma unroll
    for (int i = 0; i < 8; ++i) {
        int row = rowBase + ty * 8 + i;
        if (row >= M) continue;
        float rs = 1.0f;
        if (dinv) { float di = dinv[row]; rs = fmaf(di, colsum[row], di * di); }
        float v[8];
#pragma unroll
        for (int j = 0; j < 8; ++j) {
            v[j] = acc[i][j] + rs * bb[j];
            s1[j] += v[j];
            s2[j] += v[j] * v[j];
        }
        *(float4*)&C[(size_t)row * 128 + c0] = *(float4*)&v[0];
        *(float4*)&C[(size_t)row * 128 + c1] = *(float4*)&v[4];
    }
    if (statsP) {
        float* sp = statsP + (blockIdx.x & 63) * 256;
        // reduce s1 over ty via LDS (unique (ty,col) slots)
#pragma unroll
        for (int j = 0; j < 4; ++j) { sA[ty][c0 + j] = s1[j]; sA[ty][c1 + j] = s1[4 + j]; }
        __syncthreads();
        if (tid < 128) {
            float t = 0.f;
#pragma unroll
            for (int k = 0; k < 16; ++k) t += sA[k][tid];
            atomicAdd(&sp[tid], t);
        }
        __syncthreads();
#pragma unroll
        for (int j = 0; j < 4; ++j) { sA[ty][c0 + j] = s2[j]; sA[ty][c1 + j] = s2[4 + j]; }
        __syncthreads();
        if (tid < 128) {
            float t = 0.f;
#pragma unroll
            for (int k = 0; k < 16; ++k) t += sA[k][tid];
            atomicAdd(&sp[128 + tid], t);
        }
    }
}

// ---------------- layer-3 GEMM (N<=64) + fused log_softmax ----------------

__global__ __launch_bounds__(256) void gemm40_softmax(
        const float* __restrict__ A, const float* __restrict__ B,
        const float* __restrict__ bias,
        const float* __restrict__ dinv, const float* __restrict__ colsum,
        float* __restrict__ out, int M, int N, int K) {
    __shared__ float sA[16][132];
    __shared__ float sB[16][68];
    __shared__ float sOut[128][41];
    int tid = threadIdx.x;
    int rowBase = blockIdx.x * 128;
    int tx = tid & 15;
    int ty = tid >> 4;
    float acc[8][4] = {};

    int aRow = tid >> 1;
    int aK   = (tid & 1) * 8;
    int bK   = tid >> 4;
    int bCol = (tid & 15) * 4;

    for (int k0 = 0; k0 < K; k0 += 16) {
        int gRow = rowBase + aRow;
        if (gRow >= M) gRow = M - 1;
        const float* ap = A + (size_t)gRow * K + k0 + aK;
        float4 a0 = *(const float4*)ap;
        float4 a1 = *(const float4*)(ap + 4);
        sA[aK + 0][aRow] = a0.x;
        sA[aK + 1][aRow] = a0.y;
        sA[aK + 2][aRow] = a0.z;
        sA[aK + 3][aRow] = a0.w;
        sA[aK + 4][aRow] = a1.x;
        sA[aK + 5][aRow] = a1.y;
        sA[aK + 6][aRow] = a1.z;
        sA[aK + 7][aRow] = a1.w;
#pragma unroll
        for (int j = 0; j < 4; ++j) {
            int col = bCol + j;
            sB[bK][col] = (col < N) ? B[(size_t)(k0 + bK) * N + col] : 0.0f;
        }
        __syncthreads();
#pragma unroll
        for (int kk = 0; kk < 16; ++kk) {
            float4 av0 = *(const float4*)&sA[kk][ty * 8];
            float4 av1 = *(const float4*)&sA[kk][ty * 8 + 4];
            float4 bv  = *(const float4*)&sB[kk][tx * 4];
            float a[8] = {av0.x, av0.y, av0.z, av0.w, av1.x, av1.y, av1.z, av1.w};
            float b[4] = {bv.x, bv.y, bv.z, bv.w};
#pragma unroll
            for (int i = 0; i < 8; ++i)
#pragma unroll
                for (int j = 0; j < 4; ++j)
                    acc[i][j] = fmaf(a[i], b[j], acc[i][j]);
        }
        __syncthreads();
    }

    int colOut = tx * 4;
    float bb[4];
#pragma unroll
    for (int j = 0; j < 4; ++j) bb[j] = (colOut + j < N) ? bias[colOut + j] : 0.0f;
#pragma unroll
    for (int i = 0; i < 8; ++i) {
        int rowL = ty * 8 + i;
        int row = rowBase + rowL;
        float rs = 1.0f;
        if (row < M) { float di = dinv[row]; rs = fmaf(di, colsum[row], di * di); }
#pragma unroll
        for (int j = 0; j < 4; ++j)
            if (colOut + j < N) sOut[rowL][colOut + j] = acc[i][j] + rs * bb[j];
    }
    __syncthreads();
    if (tid < 128) {
        int row = rowBase + tid;
        if (row < M) {
            float mx = -INFINITY;
            for (int c = 0; c < N; ++c) mx = fmaxf(mx, sOut[tid][c]);
            float sm = 0.f;
            for (int c = 0; c < N; ++c) sm += expf(sOut[tid][c] - mx);
            float lg = mx + logf(sm);
            float* op = out + (size_t)row * N;
            for (int c = 0; c < N; ++c) op[c] = sOut[tid][c] - lg;
        }
    }
}

// ---------------- fp32 aggregation (layer 1) + fused BN-stats partials ----------------

__global__ __launch_bounds__(256) void aggregate128_par(
        const float* __restrict__ h, const float* __restrict__ dinv,
        const int4* __restrict__ epack,
        const int* __restrict__ start, const int* __restrict__ indeg,
        float* __restrict__ out, float* __restrict__ statsP, int n, int E) {
    __shared__ int   sIdx[256];
    __shared__ float sW[256];
    __shared__ float red[8][132];
    int node = blockIdx.x;
    int tid = threadIdx.x;
    int c4 = (tid & 31) * 4;
    int slot = tid >> 5;
    float di = dinv[node];
    int s0 = start[node];
    int len = indeg[node];
    if (s0 < 0) s0 = 0;
    if (len < 0) len = 0;
    if (s0 + len > E) len = (E - s0 > 0) ? (E - s0) : 0;

    float4 acc = {0.f, 0.f, 0.f, 0.f};
    for (int chunk = 0; chunk < len; chunk += 256) {
        int m = len - chunk; if (m > 256) m = 256;
        if (tid < m) {
            int4 e = epack[s0 + chunk + tid];
            int s = e.x;
            float w = __int_as_float(e.y) * di;
            if ((unsigned)s >= (unsigned)n) { s = node; w = 0.f; }
            sIdx[tid] = s; sW[tid] = w;
        }
        __syncthreads();
        int j = slot;
        for (; j + 8 < m; j += 16) {
            int sa = sIdx[j], sb = sIdx[j + 8];
            float wa = sW[j], wb = sW[j + 8];
            float4 va = *(const float4*)(h + (size_t)sa * 128 + c4);
            float4 vb = *(const float4*)(h + (size_t)sb * 128 + c4);
            acc.x = fmaf(va.x, wa, acc.x); acc.y = fmaf(va.y, wa, acc.y);
            acc.z = fmaf(va.z, wa, acc.z); acc.w = fmaf(va.w, wa, acc.w);
            acc.x = fmaf(vb.x, wb, acc.x); acc.y = fmaf(vb.y, wb, acc.y);
            acc.z = fmaf(vb.z, wb, acc.z); acc.w = fmaf(vb.w, wb, acc.w);
        }
        if (j < m) {
            int sa = sIdx[j];
            float wa = sW[j];
            float4 va = *(const float4*)(h + (size_t)sa * 128 + c4);
            acc.x = fmaf(va.x, wa, acc.x); acc.y = fmaf(va.y, wa, acc.y);
            acc.z = fmaf(va.z, wa, acc.z); acc.w = fmaf(va.w, wa, acc.w);
        }
        __syncthreads();
    }
    *(float4*)&red[slot][c4] = acc;
    __syncthreads();
    if (tid < 128) {
        int c = tid;
        float r = h[(size_t)node * 128 + c] * di * di;    // self loop
#pragma unroll
        for (int s = 0; s < 8; ++s) r += red[s][c];
        out[(size_t)node * 128 + c] = r;
        float* sp = statsP + (blockIdx.x & 63) * 256;
        atomicAdd(&sp[c], r);
        atomicAdd(&sp[128 + c], r * r);
    }
}

// ---------------- u8 aggregation (layers 2,3): one WAVE per node ----------------

__device__ __forceinline__ void unpack_fma(float* acc, uint4 v, float w) {
    acc[0]  = fmaf((float)(v.x & 255), w, acc[0]);
    acc[1]  = fmaf((float)((v.x >> 8) & 255), w, acc[1]);
    acc[2]  = fmaf((float)((v.x >> 16) & 255), w, acc[2]);
    acc[3]  = fmaf((float)(v.x >> 24), w, acc[3]);
    acc[4]  = fmaf((float)(v.y & 255), w, acc[4]);
    acc[5]  = fmaf((float)((v.y >> 8) & 255), w, acc[5]);
    acc[6]  = fmaf((float)((v.y >> 16) & 255), w, acc[6]);
    acc[7]  = fmaf((float)(v.y >> 24), w, acc[7]);
    acc[8]  = fmaf((float)(v.z & 255), w, acc[8]);
    acc[9]  = fmaf((float)((v.z >> 8) & 255), w, acc[9]);
    acc[10] = fmaf((float)((v.z >> 16) & 255), w, acc[10]);
    acc[11] = fmaf((float)(v.z >> 24), w, acc[11]);
    acc[12] = fmaf((float)(v.w & 255), w, acc[12]);
    acc[13] = fmaf((float)((v.w >> 8) & 255), w, acc[13]);
    acc[14] = fmaf((float)((v.w >> 16) & 255), w, acc[14]);
    acc[15] = fmaf((float)(v.w >> 24), w, acc[15]);
}

__global__ __launch_bounds__(256) void aggregate_q8_wave(
        const unsigned char* __restrict__ q, const float* __restrict__ dinv,
        const float* __restrict__ gscale, const int4* __restrict__ epack, int gsel,
        const int* __restrict__ start, const int* __restrict__ indeg,
        float* __restrict__ out, int n, int E) {
    int node = blockIdx.x * 4 + (threadIdx.x >> 6);
    if (node >= n) return;
    int lane = threadIdx.x & 63;
    int slot = lane >> 3;      // 0..7
    int sl   = lane & 7;       // covers bytes sl*16..sl*16+15
    float di = dinv[node];
    int s0 = start[node];
    int len = indeg[node];
    if (s0 < 0) s0 = 0;
    if (len < 0) len = 0;
    if (s0 + len > E) len = (E - s0 > 0) ? (E - s0) : 0;

    float acc[16] = {};
    int j = slot;
    for (; j + 8 < len; j += 16) {
        int4 ea = epack[s0 + j];
        int4 eb = epack[s0 + j + 8];
        int sa = ea.x, sb = eb.x;
        float wa = __int_as_float(gsel == 2 ? ea.z : ea.w) * di;
        float wb = __int_as_float(gsel == 2 ? eb.z : eb.w) * di;
        if ((unsigned)sa >= (unsigned)n) { sa = node; wa = 0.f; }
        if ((unsigned)sb >= (unsigned)n) { sb = node; wb = 0.f; }
        uint4 va = *(const uint4*)(q + (size_t)sa * 128 + sl * 16);
        uint4 vb = *(const uint4*)(q + (size_t)sb * 128 + sl * 16);
        unpack_fma(acc, va, wa);
        unpack_fma(acc, vb, wb);
    }
    if (j < len) {
        int4 ea = epack[s0 + j];
        int sa = ea.x;
        float wa = __int_as_float(gsel == 2 ? ea.z : ea.w) * di;
        if ((unsigned)sa >= (unsigned)n) { sa = node; wa = 0.f; }
        uint4 va = *(const uint4*)(q + (size_t)sa * 128 + sl * 16);
        unpack_fma(acc, va, wa);
    }
#pragma unroll
    for (int o = 8; o < 64; o <<= 1) {
#pragma unroll
        for (int k = 0; k < 16; ++k) acc[k] += __shfl_xor(acc[k], o);
    }
    if (slot == 0) {
        uint4 vs = *(const uint4*)(q + (size_t)node * 128 + sl * 16);
        unpack_fma(acc, vs, gscale[node] * di * di);   // self loop
        float* op = out + (size_t)node * 128 + sl * 16;
        *(float4*)(op + 0)  = *(float4*)&acc[0];
        *(float4*)(op + 4)  = *(float4*)&acc[4];
        *(float4*)(op + 8)  = *(float4*)&acc[8];
        *(float4*)(op + 12) = *(float4*)&acc[12];
    }
}

// ---------------- BN partial reduce: 64 copies -> copy 0 ----------------

__global__ void bn_reduce(float* __restrict__ statsP) {
    int t = threadIdx.x;   // 256
    float s = 0.f;
    for (int k = 0; k < 64; ++k) s += statsP[k * 256 + t];
    __syncthreads();
    statsP[t] = s;
}

// BN finalize (per-thread) + affine + ReLU + 4-bit fake-quant -> u8
__global__ void bn_apply_quant_u8(const float* __restrict__ x,
                                  const float* __restrict__ sums,
                                  const float* __restrict__ sumsq,
                                  const float* __restrict__ g, const float* __restrict__ b,
                                  const float* __restrict__ gs,
                                  unsigned char* __restrict__ out, int n) {
    int idx = blockIdx.x * blockDim.x + threadIdx.x;
    if (idx >= n * 128) return;
    int c = idx & 127;
    int r = idx >> 7;
    float m  = sums[c] / (float)n;
    float vr = sumsq[c] / (float)n - m * m;
    float a  = g[c] * (1.0f / sqrtf(vr + 1e-5f));
    float bp = b[c] - m * a;
    float v = a * x[idx] + bp;
    v = fmaxf(v, 0.0f);
    float qv = fminf(fmaxf(v / gs[r], 0.0f), 15.0f);
    out[idx] = (unsigned char)rintf(qv);   // round-half-even
}

// ---------------- launch ----------------

extern "C" void kernel_launch(void* const* d_in, const int* in_sizes, int n_in,
                              void* d_out, int out_size, void* d_ws, size_t ws_size,
                              hipStream_t stream) {
    float*       xbuf = (float*)d_in[0];          // reused as scratch after layer-1 GEMM
    const int*   ei   = (const int*)d_in[1];
    const float* W1   = (const float*)d_in[2];
    const float* b1   = (const float*)d_in[3];
    const float* a1   = (const float*)d_in[4];
    const float* W2   = (const float*)d_in[5];
    const float* b2   = (const float*)d_in[6];
    const float* a2   = (const float*)d_in[7];
    const float* g2   = (const float*)d_in[8];
    const float* W3   = (const float*)d_in[9];
    const float* b3   = (const float*)d_in[10];
    const float* a3   = (const float*)d_in[11];
    const float* g3   = (const float*)d_in[12];
    const float* bn1g = (const float*)d_in[13];
    const float* bn1b = (const float*)d_in[14];
    const float* bn2g = (const float*)d_in[15];
    const float* bn2b = (const float*)d_in[16];

    const int n = in_sizes[0] / 128;      // 50000
    const int E = in_sizes[1] / 2;        // 800000
    const int C = in_sizes[9] / 128;      // 40
    const int* src = ei;
    const int* dst = ei + E;

    // ---- workspace layout: zeroed region FIRST ----
    char* wsp = (char*)d_ws;
    size_t off = 0;
    auto take = [&](size_t bytes) -> void* {
        void* p = wsp + off;
        off += (bytes + 255) & ~(size_t)255;
        return p;
    };
    int*   indeg   = (int*)take((size_t)n * 4);
    int*   counter = (int*)take(4);
    float* colsum  = (float*)take((size_t)n * 4);
    float* stats1  = (float*)take(64 * 256 * 4);     // 64 partial copies: sums|sumsq
    float* stats2  = (float*)take(64 * 256 * 4);
    size_t zeroBytes = off;
    int*   startA  = (int*)take((size_t)n * 4);
    int*   cursor  = (int*)take((size_t)n * 4);
    float* dinv    = (float*)take((size_t)n * 4);
    int4*  epack   = (int4*)take((size_t)E * 16);
    float* w1q     = (float*)take(128 * 128 * 4);
    float* w2q     = (float*)take(128 * 128 * 4);
    float* w3q     = (float*)take((size_t)128 * C * 4);
    unsigned char* qbuf = (unsigned char*)take((size_t)n * 128);
    float* hbuf    = (float*)take((size_t)n * 128 * 4);

    float* outF  = (float*)d_out;

    // ---- setup ----
    hipMemsetAsync(d_ws, 0, zeroBytes, stream);
    count_indeg<<<(E + 255) / 256, 256, 0, stream>>>(dst, E, indeg);
    const int nW = 128 * 128 + 128 * 128 + 128 * C;
    int setupN = (n > nW) ? n : nW;
    setup_misc<<<(setupN + 255) / 256, 256, 0, stream>>>(
        indeg, dinv, startA, cursor, counter, n,
        W1, a1, W2, a2, W3, a3, w1q, w2q, w3q, 128 * 128, 128 * 128, 128 * C);
    fill_csr_packed<<<(E + 255) / 256, 256, 0, stream>>>(src, dst, E, cursor, dinv,
                                                         g2, g3, epack, colsum, n);

    const int gElem128 = (n * 128 + 255) / 256;
    const int gWave = (n + 3) / 4;
    const int gRow128 = (n + 127) / 128;

    // ---- layer 1 ----
    gemm128_bias<<<gRow128, 256, 0, stream>>>(xbuf, w1q, b1, nullptr, nullptr,
                                              hbuf, nullptr, n, 128);
    aggregate128_par<<<n, 256, 0, stream>>>(hbuf, dinv, epack, startA, indeg,
                                            xbuf, stats1, n, E);
    bn_reduce<<<1, 256, 0, stream>>>(stats1);
    bn_apply_quant_u8<<<gElem128, 256, 0, stream>>>(xbuf, stats1, stats1 + 128,
                                                    bn1g, bn1b, g2, qbuf, n);

    // ---- layer 2: aggregate(q)*W + rowsum*b (stats fused into GEMM) ----
    aggregate_q8_wave<<<gWave, 256, 0, stream>>>(qbuf, dinv, g2, epack, 2, startA, indeg,
                                                 hbuf, n, E);
    gemm128_bias<<<gRow128, 256, 0, stream>>>(hbuf, w2q, b2, dinv, colsum,
                                              xbuf, stats2, n, 128);
    bn_reduce<<<1, 256, 0, stream>>>(stats2);
    bn_apply_quant_u8<<<gElem128, 256, 0, stream>>>(xbuf, stats2, stats2 + 128,
                                                    bn2g, bn2b, g3, qbuf, n);

    // ---- layer 3: aggregate(q)*W3 + rowsum*b3, softmax fused ----
    aggregate_q8_wave<<<gWave, 256, 0, stream>>>(qbuf, dinv, g3, epack, 3, startA, indeg,
                                                 hbuf, n, E);
    gemm40_softmax<<<gRow128, 256, 0, stream>>>(hbuf, w3q, b3, dinv, colsum,
                                                outF, n, C, 128);
}

// Round 11
// 464.508 us; speedup vs baseline: 1.3080x; 1.0327x over previous
//
#include <hip/hip_runtime.h>
#include <hip/hip_bf16.h>
#include <math.h>

// ---------------- graph structure ----------------

__global__ void count_indeg(const int* __restrict__ dst, int e, int* __restrict__ indeg) {
    int i = blockIdx.x * blockDim.x + threadIdx.x;
    if (i < e) atomicAdd(&indeg[dst[i]], 1);
}

// fused setup: dinv + ranges + nodeW table (i < n)  |  weight fake-quant (i < nW)
__global__ void setup_misc(const int* __restrict__ indeg, float* __restrict__ dinv,
                           int* __restrict__ start, int* __restrict__ cursor,
                           int* __restrict__ counter,
                           const float* __restrict__ g2, const float* __restrict__ g3,
                           float4* __restrict__ nodeW, int n,
                           const float* __restrict__ W1, const float* __restrict__ a1,
                           const float* __restrict__ W2, const float* __restrict__ a2,
                           const float* __restrict__ W3, const float* __restrict__ a3,
                           float* __restrict__ w1q, float* __restrict__ w2q,
                           float* __restrict__ w3q, int n1, int n2, int n3) {
    int i = blockIdx.x * blockDim.x + threadIdx.x;
    if (i < n) {
        int d = indeg[i];
        float ds = 1.0f / sqrtf((float)(d + 1));
        dinv[i] = ds;
        nodeW[i] = make_float4(ds, ds * g2[i], ds * g3[i], 0.0f);
        int s = atomicAdd(counter, d);
        start[i] = s;
        cursor[i] = s;
    }
    const float* w; const float* a; float* o; int k;
    if (i < n1) { w = W1; a = a1; o = w1q; k = i; }
    else if (i < n1 + n2) { w = W2; a = a2; o = w2q; k = i - n1; }
    else if (i < n1 + n2 + n3) { w = W3; a = a3; o = w3q; k = i - n1 - n2; }
    else return;
    float s = a[0];
    float v = w[k] / s;
    v = fminf(fmaxf(v, -8.0f), 7.0f);
    o[k] = rintf(v) * s;   // round-half-even, matches jnp.round
}

// minimal CSR fill: one atomic + one 4B store per edge
__global__ void fill_csr_min(const int* __restrict__ src, const int* __restrict__ dst,
                             int e, int* __restrict__ cursor, int* __restrict__ ssrc, int n) {
    int i = blockIdx.x * blockDim.x + threadIdx.x;
    if (i >= e) return;
    int s = src[i];
    int p = atomicAdd(&cursor[dst[i]], 1);
    if (p >= 0 && p < e) ssrc[p] = ((unsigned)s < (unsigned)n) ? s : -1;
}

// ---------------- GEMM 128-col + optional fused BN-stats partials ----------------
// C = A@B + rs*bias, rs = di^2 + colsumS[row] (colsumS already includes di factor).

__global__ __launch_bounds__(256) void gemm128_bias(
        const float* __restrict__ A, const float* __restrict__ B,
        const float* __restrict__ bias,
        const float* __restrict__ dinv, const float* __restrict__ colsumS,
        float* __restrict__ C, float* __restrict__ statsP, int M, int K) {
    __shared__ float sA[16][132];
    __shared__ float sB[16][132];
    int tid = threadIdx.x;
    int rowBase = blockIdx.x * 128;
    int tx = tid & 15;
    int ty = tid >> 4;
    float acc[8][8] = {};

    int aRow = tid >> 1;
    int aK   = (tid & 1) * 8;
    int bK   = tid >> 4;
    int bCol = (tid & 15) * 8;

    for (int k0 = 0; k0 < K; k0 += 16) {
        int gRow = rowBase + aRow;
        if (gRow >= M) gRow = M - 1;
        const float* ap = A + (size_t)gRow * K + k0 + aK;
        float4 a0 = *(const float4*)ap;
        float4 a1 = *(const float4*)(ap + 4);
        sA[aK + 0][aRow] = a0.x;
        sA[aK + 1][aRow] = a0.y;
        sA[aK + 2][aRow] = a0.z;
        sA[aK + 3][aRow] = a0.w;
        sA[aK + 4][aRow] = a1.x;
        sA[aK + 5][aRow] = a1.y;
        sA[aK + 6][aRow] = a1.z;
        sA[aK + 7][aRow] = a1.w;
        const float* bp = B + (size_t)(k0 + bK) * 128 + bCol;
        *(float4*)&sB[bK][bCol]     = *(const float4*)bp;
        *(float4*)&sB[bK][bCol + 4] = *(const float4*)(bp + 4);
        __syncthreads();

#pragma unroll
        for (int kk = 0; kk < 16; ++kk) {
            float4 av0 = *(const float4*)&sA[kk][ty * 8];
            float4 av1 = *(const float4*)&sA[kk][ty * 8 + 4];
            float4 bv0 = *(const float4*)&sB[kk][tx * 4];
            float4 bv1 = *(const float4*)&sB[kk][64 + tx * 4];
            float a[8] = {av0.x, av0.y, av0.z, av0.w, av1.x, av1.y, av1.z, av1.w};
            float b[8] = {bv0.x, bv0.y, bv0.z, bv0.w, bv1.x, bv1.y, bv1.z, bv1.w};
#pragma unroll
            for (int i = 0; i < 8; ++i)
#pragma unroll
                for (int j = 0; j < 8; ++j)
                    acc[i][j] = fmaf(a[i], b[j], acc[i][j]);
        }
        __syncthreads();
    }

    int c0 = tx * 4, c1 = 64 + tx * 4;
    float bb[8];
#pragma unroll
    for (int j = 0; j < 4; ++j) { bb[j] = bias[c0 + j]; bb[4 + j] = bias[c1 + j]; }
    float s1[8] = {}, s2[8] = {};
#pragma unroll
    for (int i = 0; i < 8; ++i) {
        int row = rowBase + ty * 8 + i;
        if (row >= M) continue;
        float rs = 1.0f;
        if (dinv) { float di = dinv[row]; rs = di * di + colsumS[row]; }
        float v[8];
#pragma unroll
        for (int j = 0; j < 8; ++j) {
            v[j] = acc[i][j] + rs * bb[j];
            s1[j] += v[j];
            s2[j] += v[j] * v[j];
        }
        *(float4*)&C[(size_t)row * 128 + c0] = *(float4*)&v[0];
        *(float4*)&C[(size_t)row * 128 + c1] = *(float4*)&v[4];
    }
    if (statsP) {
        float* sp = statsP + (blockIdx.x & 63) * 256;
#pragma unroll
        for (int j = 0; j < 4; ++j) { sA[ty][c0 + j] = s1[j]; sA[ty][c1 + j] = s1[4 + j]; }
        __syncthreads();
        if (tid < 128) {
            float t = 0.f;
#pragma unroll
            for (int k = 0; k < 16; ++k) t += sA[k][tid];
            atomicAdd(&sp[tid], t);
        }
        __syncthreads();
#pragma unroll
        for (int j = 0; j < 4; ++j) { sA[ty][c0 + j] = s2[j]; sA[ty][c1 + j] = s2[4 + j]; }
        __syncthreads();
        if (tid < 128) {
            float t = 0.f;
#pragma unroll
            for (int k = 0; k < 16; ++k) t += sA[k][tid];
            atomicAdd(&sp[128 + tid], t);
        }
    }
}

// ---------------- layer-3 GEMM (N<=64) + fused log_softmax ----------------

__global__ __launch_bounds__(256) void gemm40_softmax(
        const float* __restrict__ A, const float* __restrict__ B,
        const float* __restrict__ bias,
        const float* __restrict__ dinv, const float* __restrict__ colsumS,
        float* __restrict__ out, int M, int N, int K) {
    __shared__ float sA[16][132];
    __shared__ float sB[16][68];
    __shared__ float sOut[128][41];
    int tid = threadIdx.x;
    int rowBase = blockIdx.x * 128;
    int tx = tid & 15;
    int ty = tid >> 4;
    float acc[8][4] = {};

    int aRow = tid >> 1;
    int aK   = (tid & 1) * 8;
    int bK   = tid >> 4;
    int bCol = (tid & 15) * 4;

    for (int k0 = 0; k0 < K; k0 += 16) {
        int gRow = rowBase + aRow;
        if (gRow >= M) gRow = M - 1;
        const float* ap = A + (size_t)gRow * K + k0 + aK;
        float4 a0 = *(const float4*)ap;
        float4 a1 = *(const float4*)(ap + 4);
        sA[aK + 0][aRow] = a0.x;
        sA[aK + 1][aRow] = a0.y;
        sA[aK + 2][aRow] = a0.z;
        sA[aK + 3][aRow] = a0.w;
        sA[aK + 4][aRow] = a1.x;
        sA[aK + 5][aRow] = a1.y;
        sA[aK + 6][aRow] = a1.z;
        sA[aK + 7][aRow] = a1.w;
#pragma unroll
        for (int j = 0; j < 4; ++j) {
            int col = bCol + j;
            sB[bK][col] = (col < N) ? B[(size_t)(k0 + bK) * N + col] : 0.0f;
        }
        __syncthreads();
#pragma unroll
        for (int kk = 0; kk < 16; ++kk) {
            float4 av0 = *(const float4*)&sA[kk][ty * 8];
            float4 av1 = *(const float4*)&sA[kk][ty * 8 + 4];
            float4 bv  = *(const float4*)&sB[kk][tx * 4];
            float a[8] = {av0.x, av0.y, av0.z, av0.w, av1.x, av1.y, av1.z, av1.w};
            float b[4] = {bv.x, bv.y, bv.z, bv.w};
#pragma unroll
            for (int i = 0; i < 8; ++i)
#pragma unroll
                for (int j = 0; j < 4; ++j)
                    acc[i][j] = fmaf(a[i], b[j], acc[i][j]);
        }
        __syncthreads();
    }

    int colOut = tx * 4;
    float bb[4];
#pragma unroll
    for (int j = 0; j < 4; ++j) bb[j] = (colOut + j < N) ? bias[colOut + j] : 0.0f;
#pragma unroll
    for (int i = 0; i < 8; ++i) {
        int rowL = ty * 8 + i;
        int row = rowBase + rowL;
        float rs = 1.0f;
        if (row < M) { float di = dinv[row]; rs = di * di + colsumS[row]; }
#pragma unroll
        for (int j = 0; j < 4; ++j)
            if (colOut + j < N) sOut[rowL][colOut + j] = acc[i][j] + rs * bb[j];
    }
    __syncthreads();
    if (tid < 128) {
        int row = rowBase + tid;
        if (row < M) {
            float mx = -INFINITY;
            for (int c = 0; c < N; ++c) mx = fmaxf(mx, sOut[tid][c]);
            float sm = 0.f;
            for (int c = 0; c < N; ++c) sm += expf(sOut[tid][c] - mx);
            float lg = mx + logf(sm);
            float* op = out + (size_t)row * N;
            for (int c = 0; c < N; ++c) op[c] = sOut[tid][c] - lg;
        }
    }
}

// ---------------- fp32 aggregation (layer 1) + BN-stats + colsumS ----------------
// colsumS[node] = sum_e dinv[src]*di  (weights staged already include *di)

__global__ __launch_bounds__(256) void aggregate128_par(
        const float* __restrict__ h, const float* __restrict__ dinv,
        const float* __restrict__ nodeWf,   // float4 table viewed as float[4n]
        const int* __restrict__ start, const int* __restrict__ indeg,
        const int* __restrict__ ssrc, float* __restrict__ out,
        float* __restrict__ statsP, float* __restrict__ colsumS, int n, int E) {
    __shared__ int   sIdx[256];
    __shared__ float sW[256];
    __shared__ float red[8][132];
    __shared__ float wpart[4];
    int node = blockIdx.x;
    int tid = threadIdx.x;
    int c4 = (tid & 31) * 4;
    int slot = tid >> 5;
    float di = dinv[node];
    int s0 = start[node];
    int len = indeg[node];
    if (s0 < 0) s0 = 0;
    if (len < 0) len = 0;
    if (s0 + len > E) len = (E - s0 > 0) ? (E - s0) : 0;

    float4 acc = {0.f, 0.f, 0.f, 0.f};
    float wacc = 0.f;
    for (int chunk = 0; chunk < len; chunk += 256) {
        int m = len - chunk; if (m > 256) m = 256;
        if (tid < m) {
            int s = ssrc[s0 + chunk + tid];
            float w;
            if ((unsigned)s >= (unsigned)n) { s = node; w = 0.f; }
            else w = nodeWf[(size_t)s * 4] * di;
            sIdx[tid] = s; sW[tid] = w; wacc += w;
        }
        __syncthreads();
        int j = slot;
        for (; j + 8 < m; j += 16) {
            int sa = sIdx[j], sb = sIdx[j + 8];
            float wa = sW[j], wb = sW[j + 8];
            float4 va = *(const float4*)(h + (size_t)sa * 128 + c4);
            float4 vb = *(const float4*)(h + (size_t)sb * 128 + c4);
            acc.x = fmaf(va.x, wa, acc.x); acc.y = fmaf(va.y, wa, acc.y);
            acc.z = fmaf(va.z, wa, acc.z); acc.w = fmaf(va.w, wa, acc.w);
            acc.x = fmaf(vb.x, wb, acc.x); acc.y = fmaf(vb.y, wb, acc.y);
            acc.z = fmaf(vb.z, wb, acc.z); acc.w = fmaf(vb.w, wb, acc.w);
        }
        if (j < m) {
            int sa = sIdx[j];
            float wa = sW[j];
            float4 va = *(const float4*)(h + (size_t)sa * 128 + c4);
            acc.x = fmaf(va.x, wa, acc.x); acc.y = fmaf(va.y, wa, acc.y);
            acc.z = fmaf(va.z, wa, acc.z); acc.w = fmaf(va.w, wa, acc.w);
        }
        __syncthreads();
    }
    // per-wave reduce of wacc (no barrier), then one slot each
#pragma unroll
    for (int o = 1; o < 64; o <<= 1) wacc += __shfl_xor(wacc, o);
    if ((tid & 63) == 0) wpart[tid >> 6] = wacc;
    *(float4*)&red[slot][c4] = acc;
    __syncthreads();
    if (tid == 0) colsumS[node] = wpart[0] + wpart[1] + wpart[2] + wpart[3];
    if (tid < 128) {
        int c = tid;
        float r = h[(size_t)node * 128 + c] * di * di;    // self loop
#pragma unroll
        for (int s = 0; s < 8; ++s) r += red[s][c];
        out[(size_t)node * 128 + c] = r;
        float* sp = statsP + (blockIdx.x & 63) * 256;
        atomicAdd(&sp[c], r);
        atomicAdd(&sp[128 + c], r * r);
    }
}

// ---------------- u8 aggregation (layers 2,3): one WAVE per node ----------------
// weight from nodeW table component gsel (1 = dinv*g2, 2 = dinv*g3)

__device__ __forceinline__ void unpack_fma(float* acc, uint4 v, float w) {
    acc[0]  = fmaf((float)(v.x & 255), w, acc[0]);
    acc[1]  = fmaf((float)((v.x >> 8) & 255), w, acc[1]);
    acc[2]  = fmaf((float)((v.x >> 16) & 255), w, acc[2]);
    acc[3]  = fmaf((float)(v.x >> 24), w, acc[3]);
    acc[4]  = fmaf((float)(v.y & 255), w, acc[4]);
    acc[5]  = fmaf((float)((v.y >> 8) & 255), w, acc[5]);
    acc[6]  = fmaf((float)((v.y >> 16) & 255), w, acc[6]);
    acc[7]  = fmaf((float)(v.y >> 24), w, acc[7]);
    acc[8]  = fmaf((float)(v.z & 255), w, acc[8]);
    acc[9]  = fmaf((float)((v.z >> 8) & 255), w, acc[9]);
    acc[10] = fmaf((float)((v.z >> 16) & 255), w, acc[10]);
    acc[11] = fmaf((float)(v.z >> 24), w, acc[11]);
    acc[12] = fmaf((float)(v.w & 255), w, acc[12]);
    acc[13] = fmaf((float)((v.w >> 8) & 255), w, acc[13]);
    acc[14] = fmaf((float)((v.w >> 16) & 255), w, acc[14]);
    acc[15] = fmaf((float)(v.w >> 24), w, acc[15]);
}

__global__ __launch_bounds__(256) void aggregate_q8_wave(
        const unsigned char* __restrict__ q, const float* __restrict__ dinv,
        const float* __restrict__ gscale, const float* __restrict__ nodeWf, int gsel,
        const int* __restrict__ start, const int* __restrict__ indeg,
        const int* __restrict__ ssrc, float* __restrict__ out, int n, int E) {
    int node = blockIdx.x * 4 + (threadIdx.x >> 6);
    if (node >= n) return;
    int lane = threadIdx.x & 63;
    int slot = lane >> 3;      // 0..7
    int sl   = lane & 7;       // covers bytes sl*16..sl*16+15
    float di = dinv[node];
    int s0 = start[node];
    int len = indeg[node];
    if (s0 < 0) s0 = 0;
    if (len < 0) len = 0;
    if (s0 + len > E) len = (E - s0 > 0) ? (E - s0) : 0;

    float acc[16] = {};
    int j = slot;
    for (; j + 8 < len; j += 16) {
        int sa = ssrc[s0 + j];
        int sb = ssrc[s0 + j + 8];
        float wa, wb;
        if ((unsigned)sa >= (unsigned)n) { sa = node; wa = 0.f; }
        else wa = nodeWf[(size_t)sa * 4 + gsel] * di;
        if ((unsigned)sb >= (unsigned)n) { sb = node; wb = 0.f; }
        else wb = nodeWf[(size_t)sb * 4 + gsel] * di;
        uint4 va = *(const uint4*)(q + (size_t)sa * 128 + sl * 16);
        uint4 vb = *(const uint4*)(q + (size_t)sb * 128 + sl * 16);
        unpack_fma(acc, va, wa);
        unpack_fma(acc, vb, wb);
    }
    if (j < len) {
        int sa = ssrc[s0 + j];
        float wa;
        if ((unsigned)sa >= (unsigned)n) { sa = node; wa = 0.f; }
        else wa = nodeWf[(size_t)sa * 4 + gsel] * di;
        uint4 va = *(const uint4*)(q + (size_t)sa * 128 + sl * 16);
        unpack_fma(acc, va, wa);
    }
#pragma unroll
    for (int o = 8; o < 64; o <<= 1) {
#pragma unroll
        for (int k = 0; k < 16; ++k) acc[k] += __shfl_xor(acc[k], o);
    }
    if (slot == 0) {
        uint4 vs = *(const uint4*)(q + (size_t)node * 128 + sl * 16);
        unpack_fma(acc, vs, gscale[node] * di * di);   // self loop
        float* op = out + (size_t)node * 128 + sl * 16;
        *(float4*)(op + 0)  = *(float4*)&acc[0];
        *(float4*)(op + 4)  = *(float4*)&acc[4];
        *(float4*)(op + 8)  = *(float4*)&acc[8];
        *(float4*)(op + 12) = *(float4*)&acc[12];
    }
}

// ---------------- BN partial reduce: 64 copies -> copy 0 ----------------

__global__ void bn_reduce(float* __restrict__ statsP) {
    int t = threadIdx.x;   // 256
    float s = 0.f;
    for (int k = 0; k < 64; ++k) s += statsP[k * 256 + t];
    __syncthreads();
    statsP[t] = s;
}

// BN finalize (per-thread) + affine + ReLU + 4-bit fake-quant -> u8
__global__ void bn_apply_quant_u8(const float* __restrict__ x,
                                  const float* __restrict__ sums,
                                  const float* __restrict__ sumsq,
                                  const float* __restrict__ g, const float* __restrict__ b,
                                  const float* __restrict__ gs,
                                  unsigned char* __restrict__ out, int n) {
    int idx = blockIdx.x * blockDim.x + threadIdx.x;
    if (idx >= n * 128) return;
    int c = idx & 127;
    int r = idx >> 7;
    float m  = sums[c] / (float)n;
    float vr = sumsq[c] / (float)n - m * m;
    float a  = g[c] * (1.0f / sqrtf(vr + 1e-5f));
    float bp = b[c] - m * a;
    float v = a * x[idx] + bp;
    v = fmaxf(v, 0.0f);
    float qv = fminf(fmaxf(v / gs[r], 0.0f), 15.0f);
    out[idx] = (unsigned char)rintf(qv);   // round-half-even
}

// ---------------- launch ----------------

extern "C" void kernel_launch(void* const* d_in, const int* in_sizes, int n_in,
                              void* d_out, int out_size, void* d_ws, size_t ws_size,
                              hipStream_t stream) {
    float*       xbuf = (float*)d_in[0];          // reused as scratch after layer-1 GEMM
    const int*   ei   = (const int*)d_in[1];
    const float* W1   = (const float*)d_in[2];
    const float* b1   = (const float*)d_in[3];
    const float* a1   = (const float*)d_in[4];
    const float* W2   = (const float*)d_in[5];
    const float* b2   = (const float*)d_in[6];
    const float* a2   = (const float*)d_in[7];
    const float* g2   = (const float*)d_in[8];
    const float* W3   = (const float*)d_in[9];
    const float* b3   = (const float*)d_in[10];
    const float* a3   = (const float*)d_in[11];
    const float* g3   = (const float*)d_in[12];
    const float* bn1g = (const float*)d_in[13];
    const float* bn1b = (const float*)d_in[14];
    const float* bn2g = (const float*)d_in[15];
    const float* bn2b = (const float*)d_in[16];

    const int n = in_sizes[0] / 128;      // 50000
    const int E = in_sizes[1] / 2;        // 800000
    const int C = in_sizes[9] / 128;      // 40
    const int* src = ei;
    const int* dst = ei + E;

    // ---- workspace layout: zeroed region FIRST ----
    char* wsp = (char*)d_ws;
    size_t off = 0;
    auto take = [&](size_t bytes) -> void* {
        void* p = wsp + off;
        off += (bytes + 255) & ~(size_t)255;
        return p;
    };
    int*   indeg   = (int*)take((size_t)n * 4);
    int*   counter = (int*)take(4);
    float* stats1  = (float*)take(64 * 256 * 4);     // 64 partial copies: sums|sumsq
    float* stats2  = (float*)take(64 * 256 * 4);
    size_t zeroBytes = off;
    int*   startA  = (int*)take((size_t)n * 4);
    int*   cursor  = (int*)take((size_t)n * 4);
    float* dinv    = (float*)take((size_t)n * 4);
    float* colsumS = (float*)take((size_t)n * 4);
    float4* nodeW  = (float4*)take((size_t)n * 16);
    int*   ssrc    = (int*)take((size_t)E * 4);
    float* w1q     = (float*)take(128 * 128 * 4);
    float* w2q     = (float*)take(128 * 128 * 4);
    float* w3q     = (float*)take((size_t)128 * C * 4);
    unsigned char* qbuf = (unsigned char*)take((size_t)n * 128);
    float* hbuf    = (float*)take((size_t)n * 128 * 4);

    float* outF  = (float*)d_out;
    const float* nodeWf = (const float*)nodeW;

    // ---- setup ----
    hipMemsetAsync(d_ws, 0, zeroBytes, stream);
    count_indeg<<<(E + 255) / 256, 256, 0, stream>>>(dst, E, indeg);
    const int nW = 128 * 128 + 128 * 128 + 128 * C;
    int setupN = (n > nW) ? n : nW;
    setup_misc<<<(setupN + 255) / 256, 256, 0, stream>>>(
        indeg, dinv, startA, cursor, counter, g2, g3, nodeW, n,
        W1, a1, W2, a2, W3, a3, w1q, w2q, w3q, 128 * 128, 128 * 128, 128 * C);
    fill_csr_min<<<(E + 255) / 256, 256, 0, stream>>>(src, dst, E, cursor, ssrc, n);

    const int gElem128 = (n * 128 + 255) / 256;
    const int gWave = (n + 3) / 4;
    const int gRow128 = (n + 127) / 128;

    // ---- layer 1 ----
    gemm128_bias<<<gRow128, 256, 0, stream>>>(xbuf, w1q, b1, nullptr, nullptr,
                                              hbuf, nullptr, n, 128);
    aggregate128_par<<<n, 256, 0, stream>>>(hbuf, dinv, nodeWf, startA, indeg, ssrc,
                                            xbuf, stats1, colsumS, n, E);
    bn_reduce<<<1, 256, 0, stream>>>(stats1);
    bn_apply_quant_u8<<<gElem128, 256, 0, stream>>>(xbuf, stats1, stats1 + 128,
                                                    bn1g, bn1b, g2, qbuf, n);

    // ---- layer 2: aggregate(q)*W + rowsum*b (stats fused into GEMM) ----
    aggregate_q8_wave<<<gWave, 256, 0, stream>>>(qbuf, dinv, g2, nodeWf, 1, startA, indeg,
                                                 ssrc, hbuf, n, E);
    gemm128_bias<<<gRow128, 256, 0, stream>>>(hbuf, w2q, b2, dinv, colsumS,
                                              xbuf, stats2, n, 128);
    bn_reduce<<<1, 256, 0, stream>>>(stats2);
    bn_apply_quant_u8<<<gElem128, 256, 0, stream>>>(xbuf, stats2, stats2 + 128,
                                                    bn2g, bn2b, g3, qbuf, n);

    // ---- layer 3: aggregate(q)*W3 + rowsum*b3, softmax fused ----
    aggregate_q8_wave<<<gWave, 256, 0, stream>>>(qbuf, dinv, g3, nodeWf, 2, startA, indeg,
                                                 ssrc, hbuf, n, E);
    gemm40_softmax<<<gRow128, 256, 0, stream>>>(hbuf, w3q, b3, dinv, colsumS,
                                                outF, n, C, 128);
}